// Round 1
// baseline (234.210 us; speedup 1.0000x reference)
//
#include <hip/hip_runtime.h>
#include <stdint.h>

// MultiHeadAttention: B=2, S=2048, HIDDEN=1024, NH=16, HD=64, causal.
// R14: attn rewritten on mfma_f32_32x32x16_bf16, wave owns 32 q-rows
//      (block Q-tile 128, grid 512, pairing order qt=15-i with qt=i).
//      Rationale: old 16x16 structure re-read each K/V tile 4x from LDS
//      (every wave x whole tile) -> 96 KB LDS per 64q x 64k block-step;
//      attn was LDS-traffic/dep-chain bound (MfmaUtil 13%, VALU 30%,
//      HBM 4.5%, conflicts 0). 32x32 halves K/V fragment reads per unit
//      work (112 KB per 128q x 64k). Fully-masked diagonal steps skipped
//      per-wave (barrier kept uniform). GEMMs unchanged from R13.
// MFMA layouts (HW-verified):
//   16x16x32: A/B lane holds row[lane&15], k=(lane>>4)*8+j; C row=(lane>>4)*4+reg, col=lane&15
//   32x32x16: A/B lane holds row[lane&31], k=(lane>>5)*8+j; C row=(reg&3)+8*(reg>>2)+4*(lane>>5), col=lane&31

#define HIDDEN 1024
#define NH 16
#define HD 64
#define BATCH 2
#define SEQ 2048

typedef unsigned short u16;
typedef unsigned int u32;
typedef __attribute__((ext_vector_type(8))) short short8;   // 8 bf16
typedef __attribute__((ext_vector_type(4))) float f32x4;
typedef __attribute__((ext_vector_type(16))) float f32x16;

typedef const __attribute__((address_space(1))) u32 gu32;
typedef __attribute__((address_space(3))) u32 lu32;

__device__ __forceinline__ u16 f2bf(float f) {
    u32 u = __float_as_uint(f);
    return (u16)((u + 0x7FFFu + ((u >> 16) & 1u)) >> 16);   // RNE
}

// ---------------- fused fp32 -> bf16 conversion (x + 4 weights) -----------
__global__ void cvt_all(const float* __restrict__ x, const float* __restrict__ Wq,
                        const float* __restrict__ Wk, const float* __restrict__ Wv,
                        const float* __restrict__ Wo, u16* __restrict__ xb,
                        u16* __restrict__ wqb, u16* __restrict__ wkb,
                        u16* __restrict__ wvb, u16* __restrict__ wob) {
    const int blk = blockIdx.x;
    const float* src; u16* dst; int base;
    if (blk < 2048)      { src = x;  dst = xb;  base = blk; }
    else if (blk < 2560) { src = Wq; dst = wqb; base = blk - 2048; }
    else if (blk < 3072) { src = Wk; dst = wkb; base = blk - 2560; }
    else if (blk < 3584) { src = Wv; dst = wvb; base = blk - 3072; }
    else                 { src = Wo; dst = wob; base = blk - 3584; }
    const int i = base * 256 + threadIdx.x;
    float4 a = ((const float4*)src)[2 * i];
    float4 b = ((const float4*)src)[2 * i + 1];
    union { u16 h[8]; uint4 v; } o;
    o.h[0] = f2bf(a.x); o.h[1] = f2bf(a.y); o.h[2] = f2bf(a.z); o.h[3] = f2bf(a.w);
    o.h[4] = f2bf(b.x); o.h[5] = f2bf(b.y); o.h[6] = f2bf(b.z); o.h[7] = f2bf(b.w);
    ((uint4*)dst)[i] = o.v;
}

// ---- async stage: 16 rows x 32 cols (64 B/row) per call, XOR-4 swizzle ----
__device__ __forceinline__ void stage16(const u16* __restrict__ G, int grow0,
                                        int k0, u16* lds, int rbase, int lane) {
    const int sr = lane >> 2;
    const int lc = (lane & 3) ^ (sr & 3);
    const u16* g = G + (size_t)(grow0 + rbase + sr) * 1024 + k0 + lc * 8;
    __builtin_amdgcn_global_load_lds((gu32*)g, (lu32*)(lds + rbase * 32), 16, 0, 0);
}

// ---------------- fused QKV projection ------------------------------------
// grid (24, 32). Q/K -> [B,H,S,D] direct; V -> [B,H,D,S] via LDS transpose.
__launch_bounds__(256, 3)
__global__ void gemm_qkv(const u16* __restrict__ A, const u16* __restrict__ Wqb,
                         const u16* __restrict__ Wkb, const u16* __restrict__ Wvb,
                         const float* __restrict__ bq, const float* __restrict__ bk,
                         const float* __restrict__ bv, u16* __restrict__ Qo,
                         u16* __restrict__ Ko, u16* __restrict__ Vo) {
    __shared__ u16 As[2][128 * 32];   // 2 x 8 KB
    __shared__ u16 Bs[2][128 * 32];   // 2 x 8 KB -> 32 KB total
    const int which = blockIdx.x >> 3;
    const int n0 = (blockIdx.x & 7) * 128;
    const int m0 = blockIdx.y * 128;
    const u16* Wt = (which == 0) ? Wqb : (which == 1) ? Wkb : Wvb;
    const float* bias = (which == 0) ? bq : (which == 1) ? bk : bv;
    u16* out = (which == 0) ? Qo : (which == 1) ? Ko : Vo;
    const float oscale = (which == 0) ? 0.18033688011112042f : 1.0f;  // log2e/8
    const int t = threadIdx.x;
    const int lane = t & 63, w = t >> 6, quad = lane >> 4, lm = lane & 15;
    const int wm = (w & 1) * 64, wn = (w >> 1) * 64;

    f32x4 acc[4][4] = {};

    auto stage = [&](int k0, int buf) {
        stage16(A, m0, k0, As[buf], w * 32, lane);
        stage16(A, m0, k0, As[buf], w * 32 + 16, lane);
        stage16(Wt, n0, k0, Bs[buf], w * 32, lane);
        stage16(Wt, n0, k0, Bs[buf], w * 32 + 16, lane);
    };

    stage(0, 0);
    __syncthreads();
    for (int k0 = 0; k0 < 1024; k0 += 32) {
        const int cur = (k0 >> 5) & 1;
        if (k0 + 32 < 1024) stage(k0 + 32, cur ^ 1);
        short8 af[4], bf[4];
        const int sw = (quad ^ (lm & 3)) * 8;   // swizzled slot offset (elems)
#pragma unroll
        for (int mi = 0; mi < 4; mi++)
            af[mi] = *(const short8*)(&As[cur][(wm + mi * 16 + lm) * 32] + sw);
#pragma unroll
        for (int ni = 0; ni < 4; ni++)
            bf[ni] = *(const short8*)(&Bs[cur][(wn + ni * 16 + lm) * 32] + sw);
#pragma unroll
        for (int mi = 0; mi < 4; mi++)
#pragma unroll
            for (int ni = 0; ni < 4; ni++)
                acc[mi][ni] = __builtin_amdgcn_mfma_f32_16x16x32_bf16(
                    af[mi], bf[ni], acc[mi][ni], 0, 0, 0);
        __syncthreads();   // drains vmcnt (next tile landed) + guards buf reuse
    }

    if (which == 2) {
        // V: per-wave LDS transpose -> coalesced [B,H,D,S] stores.
        u16* Tw = ((w < 2) ? (u16*)As : (u16*)Bs) + (w & 1) * 4096;
#pragma unroll
        for (int ni = 0; ni < 4; ni++) {
            const int n_loc = ni * 16 + lm;
            const float bv_ = bias[n0 + wn + n_loc];
#pragma unroll
            for (int mi = 0; mi < 4; mi++)
#pragma unroll
                for (int r = 0; r < 4; r++) {
                    const int m_loc = mi * 16 + quad * 4 + r;
                    Tw[n_loc * 64 + (((m_loc >> 3) ^ (n_loc & 7)) * 8) + (m_loc & 7)] =
                        f2bf(acc[mi][ni][r] + bv_);
                }
        }
        const int hh = (n0 + wn) >> 6;
        const int mg = m0 + wm;             // 64-aligned, never straddles batch
        const int bb = mg >> 11, s0 = mg & 2047;
        u16* outp = out + ((size_t)(bb * NH + hh) * HD) * SEQ;
        const int cm = lane & 7;            // logical m-chunk (8 elems)
#pragma unroll
        for (int i = 0; i < 8; i++) {
            const int n_loc = i * 8 + (lane >> 3);   // d
            short8 v = *(const short8*)(Tw + n_loc * 64 + ((cm ^ (n_loc & 7)) * 8));
            *(short8*)(outp + (size_t)n_loc * SEQ + s0 + cm * 8) = v;
        }
    } else {
#pragma unroll
        for (int ni = 0; ni < 4; ni++) {
            const int n = n0 + wn + ni * 16 + lm;
            const float bv_ = bias[n];
            const int h = n >> 6, d = n & 63;
#pragma unroll
            for (int mi = 0; mi < 4; mi++)
#pragma unroll
                for (int r = 0; r < 4; r++) {
                    const int m = m0 + wm + mi * 16 + quad * 4 + r;
                    const int b = m >> 11, s = m & 2047;
                    out[(((size_t)(b * NH + h) * SEQ + s) * HD) + d] =
                        f2bf((acc[mi][ni][r] + bv_) * oscale);
                }
        }
    }
}

// ---------------- output projection (R10, unchanged) ----------------------
__launch_bounds__(256, 2)
__global__ void gemm_out(const u16* __restrict__ A, const u16* __restrict__ Wt,
                         const float* __restrict__ bias, float* __restrict__ out) {
    __shared__ u16 As[2][64 * 32];    // 2 x 4 KB
    __shared__ u16 Bs[2][128 * 32];   // 2 x 8 KB -> 24 KB total
    const int n0 = blockIdx.x * 128;
    const int m0 = blockIdx.y * 64;
    const int t = threadIdx.x;
    const int lane = t & 63, w = t >> 6, quad = lane >> 4, lm = lane & 15;
    const int wm = (w & 1) * 32, wn = (w >> 1) * 64;

    f32x4 acc[2][4] = {};

    auto stage = [&](int k0, int buf) {
        stage16(A, m0, k0, As[buf], w * 16, lane);
        stage16(Wt, n0, k0, Bs[buf], w * 32, lane);
        stage16(Wt, n0, k0, Bs[buf], w * 32 + 16, lane);
    };

    stage(0, 0);
    __syncthreads();
    for (int k0 = 0; k0 < 1024; k0 += 32) {
        const int cur = (k0 >> 5) & 1;
        if (k0 + 32 < 1024) stage(k0 + 32, cur ^ 1);
        short8 af[2], bf[4];
        const int sw = (quad ^ (lm & 3)) * 8;
#pragma unroll
        for (int mi = 0; mi < 2; mi++)
            af[mi] = *(const short8*)(&As[cur][(wm + mi * 16 + lm) * 32] + sw);
#pragma unroll
        for (int ni = 0; ni < 4; ni++)
            bf[ni] = *(const short8*)(&Bs[cur][(wn + ni * 16 + lm) * 32] + sw);
#pragma unroll
        for (int mi = 0; mi < 2; mi++)
#pragma unroll
            for (int ni = 0; ni < 4; ni++)
                acc[mi][ni] = __builtin_amdgcn_mfma_f32_16x16x32_bf16(
                    af[mi], bf[ni], acc[mi][ni], 0, 0, 0);
        __syncthreads();
    }

#pragma unroll
    for (int ni = 0; ni < 4; ni++) {
        const int n = n0 + wn + ni * 16 + lm;
        const float bv_ = bias[n];
#pragma unroll
        for (int mi = 0; mi < 2; mi++)
#pragma unroll
            for (int r = 0; r < 4; r++) {
                const int m = m0 + wm + mi * 16 + quad * 4 + r;
                out[(size_t)m * 1024 + n] = acc[mi][ni][r] + bv_;
            }
    }
}

// ---------------- flash attention, causal (R14: 32x32 MFMA) ---------------
// Grid 512 blocks (pairing order: qt=15-i block paired with qt=i on same CU),
// 256 thr = 4 waves; wave owns 32 q-rows (block Q-tile 128), K-step 64,
// double-buffered LDS via global_load_lds, XOR chunk swizzle.
__launch_bounds__(256, 2)
__global__ void attn_kernel(const u16* __restrict__ Q, const u16* __restrict__ K,
                            const u16* __restrict__ Vt, u16* __restrict__ Out) {
    constexpr int LDP = 68;            // P pad: 136 B rows, 2-way max on reads
    __shared__ u16 Ks[2][64 * 64];     // 2 x 8 KB, swizzled
    __shared__ u16 Vs[2][64 * 64];     // 2 x 8 KB, swizzled
    __shared__ u16 Ps[4 * 32 * LDP];   // 17408 B -> total 50176 B
    const int t = threadIdx.x;
    const int lane = t & 63, w = t >> 6, l5 = lane & 31, hi = lane >> 5;
    const int bI = blockIdx.x;
    // longest-first + pairing: bI<256 -> qi 15..8, bI>=256 -> qi 0..7
    const int qi = (bI < 256) ? (15 - (bI >> 5)) : ((bI - 256) >> 5);
    const int bh = bI & 31;
    const int b = bh >> 4, h = bh & 15;
    const size_t base = (size_t)(b * NH + h) * SEQ * HD;
    const u16* Qg = Q + base;
    const u16* Kg = K + base;
    const u16* Vg = Vt + base;
    const int q0w = qi * 128 + w * 32;   // this wave's first q-row
    const int nk = 2 * qi + 2;           // number of 64-key steps for the block

    // Q fragments: lane holds Q[q0w + l5][kc*16 + hi*8 + j]
    short8 qf[4];
#pragma unroll
    for (int kc = 0; kc < 4; kc++)
        qf[kc] = *(const short8*)(Qg + (size_t)(q0w + l5) * HD + kc * 16 + hi * 8);

    f32x16 oacc[2] = {};
    f32x16 lacc = {};
    short8 ones;
#pragma unroll
    for (int j = 0; j < 8; j++) ones[j] = (short)0x3F80;   // bf16 1.0

    u16* Pw = Ps + w * 32 * LDP;

    const int srow = (lane >> 3);          // 0..7 within 8-row group
    const int schunk = (lane & 7) ^ srow;  // source logical chunk
    auto stage_kv = [&](int kt, int buf) {
#pragma unroll
        for (int j = 0; j < 2; j++) {
            const int row = w * 16 + j * 8 + srow;
            const u16* gk = Kg + (size_t)(kt * 64 + row) * HD + schunk * 8;
            const u16* gv = Vg + (size_t)row * SEQ + kt * 64 + schunk * 8;
            __builtin_amdgcn_global_load_lds((gu32*)gk, (lu32*)(&Ks[buf][(w * 16 + j * 8) * 64]), 16, 0, 0);
            __builtin_amdgcn_global_load_lds((gu32*)gv, (lu32*)(&Vs[buf][(w * 16 + j * 8) * 64]), 16, 0, 0);
        }
    };

    auto compute_step = [&](const u16* Kc, const u16* Vc, int kt_) {
        if (kt_ * 64 > q0w + 31) return;   // fully-masked step for this wave
        const int kbase = kt_ * 64;
        const bool diag = (kbase + 63 > q0w);
        // QK^T: S[q][key], q = crow(r,hi), key = kb*32 + l5
        f32x16 sa[2];
#pragma unroll
        for (int kb = 0; kb < 2; kb++) {
            const int kr = kb * 32 + l5;
            const u16* rowp = Kc + kr * 64;
            f32x16 a = {};
#pragma unroll
            for (int kc = 0; kc < 4; kc++) {
                short8 kf = *(const short8*)(rowp + (((2 * kc + hi) ^ (kr & 7)) * 8));
                a = __builtin_amdgcn_mfma_f32_32x32x16_bf16(qf[kc], kf, a, 0, 0, 0);
            }
            sa[kb] = a;
        }
        // mask + exp2 + P -> LDS (same-wave region; lgkmcnt orders write->read)
#pragma unroll
        for (int kb = 0; kb < 2; kb++) {
            const int key = kbase + kb * 32 + l5;
#pragma unroll
            for (int r = 0; r < 16; r++) {
                const int qloc = (r & 3) + 8 * (r >> 2) + 4 * hi;
                float s = sa[kb][r];
                if (diag && key > q0w + qloc) s = -__builtin_inff();
                Pw[qloc * LDP + kb * 32 + l5] =
                    (u16)(__float_as_uint(exp2f(s)) >> 16);
            }
        }
        // P fragments: lane holds P[l5][kc*16 + hi*8 + j]
        short8 pf[4];
#pragma unroll
        for (int kc = 0; kc < 4; kc++)
            pf[kc] = *(const short8*)(Pw + l5 * LDP + kc * 16 + hi * 8);
        // PV: O[q][d] += P[q][key] V[key][d]; V^T rows are d
#pragma unroll
        for (int n = 0; n < 2; n++) {
            const int vr = n * 32 + l5;
            const u16* rowp = Vc + vr * 64;
#pragma unroll
            for (int kc = 0; kc < 4; kc++) {
                short8 vf = *(const short8*)(rowp + (((2 * kc + hi) ^ (vr & 7)) * 8));
                oacc[n] = __builtin_amdgcn_mfma_f32_32x32x16_bf16(pf[kc], vf, oacc[n], 0, 0, 0);
            }
        }
#pragma unroll
        for (int kc = 0; kc < 4; kc++)
            lacc = __builtin_amdgcn_mfma_f32_32x32x16_bf16(pf[kc], ones, lacc, 0, 0, 0);
    };

    stage_kv(0, 0);
    __syncthreads();

    for (int kt = 0; kt < nk; kt++) {
        const int cur = kt & 1;
        if (kt + 1 < nk) stage_kv(kt + 1, cur ^ 1);   // async, no VGPRs held
        compute_step(Ks[cur], Vs[cur], kt);
        __syncthreads();   // drains vmcnt (tile kt+1 landed) + guards buf reuse
    }

#pragma unroll
    for (int r = 0; r < 16; r++) {
        const int qloc = (r & 3) + 8 * (r >> 2) + 4 * hi;
        const float iv = 1.0f / lacc[r];
        const int qq = q0w + qloc;
        u16* orow = Out + (size_t)(b * SEQ + qq) * HIDDEN + h * HD;
#pragma unroll
        for (int n = 0; n < 2; n++)
            orow[n * 32 + l5] = f2bf(oacc[n][r] * iv);
    }
}

// ---------------- launcher ------------------------------------------------
extern "C" void kernel_launch(void* const* d_in, const int* in_sizes, int n_in,
                              void* d_out, int out_size, void* d_ws, size_t ws_size,
                              hipStream_t stream) {
    const float* x  = (const float*)d_in[0];
    const float* Wq = (const float*)d_in[1];
    const float* bq = (const float*)d_in[2];
    const float* Wk = (const float*)d_in[3];
    const float* bk = (const float*)d_in[4];
    const float* Wv = (const float*)d_in[5];
    const float* bv = (const float*)d_in[6];
    const float* Wo = (const float*)d_in[7];
    const float* bo = (const float*)d_in[8];
    float* out = (float*)d_out;

    char* ws = (char*)d_ws;
    const size_t SZ_X = (size_t)4096 * 1024 * 2;   // 8 MB bf16
    const size_t SZ_W = (size_t)1024 * 1024 * 2;   // 2 MB bf16
    u16* xb    = (u16*)(ws);
    u16* wqb   = (u16*)(ws + SZ_X);
    u16* wkb   = (u16*)(ws + SZ_X + SZ_W);
    u16* wvb   = (u16*)(ws + SZ_X + 2 * SZ_W);
    u16* wob   = (u16*)(ws + SZ_X + 3 * SZ_W);
    u16* Qb    = (u16*)(ws + SZ_X + 4 * SZ_W);
    u16* Kb    = (u16*)(ws + 2 * SZ_X + 4 * SZ_W);
    u16* Vtb   = (u16*)(ws + 3 * SZ_X + 4 * SZ_W);
    u16* attnb = (u16*)(ws + 4 * SZ_X + 4 * SZ_W);

    cvt_all<<<4096, 256, 0, stream>>>(x, Wq, Wk, Wv, Wo, xb, wqb, wkb, wvb, wob);
    gemm_qkv<<<dim3(24, 32), 256, 0, stream>>>(xb, wqb, wkb, wvb, bq, bk, bv, Qb, Kb, Vtb);
    attn_kernel<<<512, 256, 0, stream>>>(Qb, Kb, Vtb, attnb);
    gemm_out<<<dim3(8, 64), 256, 0, stream>>>(attnb, wob, bo, out);
}

// Round 2
// 192.974 us; speedup vs baseline: 1.2137x; 1.2137x over previous
//
#include <hip/hip_runtime.h>
#include <stdint.h>

// MultiHeadAttention: B=2, S=2048, HIDDEN=1024, NH=16, HD=64, causal.
// R15: attn reverted to R13 16x16 structure (R14's Q-tile-128/32x32 refuted:
//      occupancy 12.7% -- 1 block/CU for most of runtime, chain exposed;
//      +2.16M bank conflicts from 32-key P-row writes). Changes vs R13:
//      (a) Ps pad-68 -> XOR-chunk swizzle, 8704->8192 B, LDS total 40960 B
//          = exactly 160KiB/4 -> 4 blocks/CU (launch_bounds 256,4).
//      (b) balanced static schedule: CU c's four resident blocks (bI = c,
//          c+256, c+512, c+768 under round-robin) get qt {31-i, 23-i, i, i+8}
//          (i = bI>>5 mapping) -> 66 steps on EVERY CU (was 52..80).
// MFMA 16x16x32 bf16 layouts (HW-verified):
//   A/B frag: lane holds row[m=lane&15][k=(lane>>4)*8 + j]
//   C/D:      row=(lane>>4)*4+reg, col=lane&15

#define HIDDEN 1024
#define NH 16
#define HD 64
#define BATCH 2
#define SEQ 2048

typedef unsigned short u16;
typedef unsigned int u32;
typedef __attribute__((ext_vector_type(8))) short short8;   // 8 bf16
typedef __attribute__((ext_vector_type(4))) float f32x4;

typedef const __attribute__((address_space(1))) u32 gu32;
typedef __attribute__((address_space(3))) u32 lu32;

__device__ __forceinline__ u16 f2bf(float f) {
    u32 u = __float_as_uint(f);
    return (u16)((u + 0x7FFFu + ((u >> 16) & 1u)) >> 16);   // RNE
}

// ---------------- fused fp32 -> bf16 conversion (x + 4 weights) -----------
__global__ void cvt_all(const float* __restrict__ x, const float* __restrict__ Wq,
                        const float* __restrict__ Wk, const float* __restrict__ Wv,
                        const float* __restrict__ Wo, u16* __restrict__ xb,
                        u16* __restrict__ wqb, u16* __restrict__ wkb,
                        u16* __restrict__ wvb, u16* __restrict__ wob) {
    const int blk = blockIdx.x;
    const float* src; u16* dst; int base;
    if (blk < 2048)      { src = x;  dst = xb;  base = blk; }
    else if (blk < 2560) { src = Wq; dst = wqb; base = blk - 2048; }
    else if (blk < 3072) { src = Wk; dst = wkb; base = blk - 2560; }
    else if (blk < 3584) { src = Wv; dst = wvb; base = blk - 3072; }
    else                 { src = Wo; dst = wob; base = blk - 3584; }
    const int i = base * 256 + threadIdx.x;
    float4 a = ((const float4*)src)[2 * i];
    float4 b = ((const float4*)src)[2 * i + 1];
    union { u16 h[8]; uint4 v; } o;
    o.h[0] = f2bf(a.x); o.h[1] = f2bf(a.y); o.h[2] = f2bf(a.z); o.h[3] = f2bf(a.w);
    o.h[4] = f2bf(b.x); o.h[5] = f2bf(b.y); o.h[6] = f2bf(b.z); o.h[7] = f2bf(b.w);
    ((uint4*)dst)[i] = o.v;
}

// ---- async stage: 16 rows x 32 cols (64 B/row) per call, XOR-4 swizzle ----
__device__ __forceinline__ void stage16(const u16* __restrict__ G, int grow0,
                                        int k0, u16* lds, int rbase, int lane) {
    const int sr = lane >> 2;
    const int lc = (lane & 3) ^ (sr & 3);
    const u16* g = G + (size_t)(grow0 + rbase + sr) * 1024 + k0 + lc * 8;
    __builtin_amdgcn_global_load_lds((gu32*)g, (lu32*)(lds + rbase * 32), 16, 0, 0);
}

// ---------------- fused QKV projection ------------------------------------
// grid (24, 32). Q/K -> [B,H,S,D] direct; V -> [B,H,D,S] via LDS transpose.
__launch_bounds__(256, 3)
__global__ void gemm_qkv(const u16* __restrict__ A, const u16* __restrict__ Wqb,
                         const u16* __restrict__ Wkb, const u16* __restrict__ Wvb,
                         const float* __restrict__ bq, const float* __restrict__ bk,
                         const float* __restrict__ bv, u16* __restrict__ Qo,
                         u16* __restrict__ Ko, u16* __restrict__ Vo) {
    __shared__ u16 As[2][128 * 32];   // 2 x 8 KB
    __shared__ u16 Bs[2][128 * 32];   // 2 x 8 KB -> 32 KB total
    const int which = blockIdx.x >> 3;
    const int n0 = (blockIdx.x & 7) * 128;
    const int m0 = blockIdx.y * 128;
    const u16* Wt = (which == 0) ? Wqb : (which == 1) ? Wkb : Wvb;
    const float* bias = (which == 0) ? bq : (which == 1) ? bk : bv;
    u16* out = (which == 0) ? Qo : (which == 1) ? Ko : Vo;
    const float oscale = (which == 0) ? 0.18033688011112042f : 1.0f;  // log2e/8
    const int t = threadIdx.x;
    const int lane = t & 63, w = t >> 6, quad = lane >> 4, lm = lane & 15;
    const int wm = (w & 1) * 64, wn = (w >> 1) * 64;

    f32x4 acc[4][4] = {};

    auto stage = [&](int k0, int buf) {
        stage16(A, m0, k0, As[buf], w * 32, lane);
        stage16(A, m0, k0, As[buf], w * 32 + 16, lane);
        stage16(Wt, n0, k0, Bs[buf], w * 32, lane);
        stage16(Wt, n0, k0, Bs[buf], w * 32 + 16, lane);
    };

    stage(0, 0);
    __syncthreads();
    for (int k0 = 0; k0 < 1024; k0 += 32) {
        const int cur = (k0 >> 5) & 1;
        if (k0 + 32 < 1024) stage(k0 + 32, cur ^ 1);
        short8 af[4], bf[4];
        const int sw = (quad ^ (lm & 3)) * 8;   // swizzled slot offset (elems)
#pragma unroll
        for (int mi = 0; mi < 4; mi++)
            af[mi] = *(const short8*)(&As[cur][(wm + mi * 16 + lm) * 32] + sw);
#pragma unroll
        for (int ni = 0; ni < 4; ni++)
            bf[ni] = *(const short8*)(&Bs[cur][(wn + ni * 16 + lm) * 32] + sw);
#pragma unroll
        for (int mi = 0; mi < 4; mi++)
#pragma unroll
            for (int ni = 0; ni < 4; ni++)
                acc[mi][ni] = __builtin_amdgcn_mfma_f32_16x16x32_bf16(
                    af[mi], bf[ni], acc[mi][ni], 0, 0, 0);
        __syncthreads();   // drains vmcnt (next tile landed) + guards buf reuse
    }

    if (which == 2) {
        // V: per-wave LDS transpose -> coalesced [B,H,D,S] stores.
        u16* Tw = ((w < 2) ? (u16*)As : (u16*)Bs) + (w & 1) * 4096;
#pragma unroll
        for (int ni = 0; ni < 4; ni++) {
            const int n_loc = ni * 16 + lm;
            const float bv_ = bias[n0 + wn + n_loc];
#pragma unroll
            for (int mi = 0; mi < 4; mi++)
#pragma unroll
                for (int r = 0; r < 4; r++) {
                    const int m_loc = mi * 16 + quad * 4 + r;
                    Tw[n_loc * 64 + (((m_loc >> 3) ^ (n_loc & 7)) * 8) + (m_loc & 7)] =
                        f2bf(acc[mi][ni][r] + bv_);
                }
        }
        const int hh = (n0 + wn) >> 6;
        const int mg = m0 + wm;             // 64-aligned, never straddles batch
        const int bb = mg >> 11, s0 = mg & 2047;
        u16* outp = out + ((size_t)(bb * NH + hh) * HD) * SEQ;
        const int cm = lane & 7;            // logical m-chunk (8 elems)
#pragma unroll
        for (int i = 0; i < 8; i++) {
            const int n_loc = i * 8 + (lane >> 3);   // d
            short8 v = *(const short8*)(Tw + n_loc * 64 + ((cm ^ (n_loc & 7)) * 8));
            *(short8*)(outp + (size_t)n_loc * SEQ + s0 + cm * 8) = v;
        }
    } else {
#pragma unroll
        for (int ni = 0; ni < 4; ni++) {
            const int n = n0 + wn + ni * 16 + lm;
            const float bv_ = bias[n];
            const int h = n >> 6, d = n & 63;
#pragma unroll
            for (int mi = 0; mi < 4; mi++)
#pragma unroll
                for (int r = 0; r < 4; r++) {
                    const int m = m0 + wm + mi * 16 + quad * 4 + r;
                    const int b = m >> 11, s = m & 2047;
                    out[(((size_t)(b * NH + h) * SEQ + s) * HD) + d] =
                        f2bf((acc[mi][ni][r] + bv_) * oscale);
                }
        }
    }
}

// ---------------- output projection (R10, unchanged) ----------------------
__launch_bounds__(256, 2)
__global__ void gemm_out(const u16* __restrict__ A, const u16* __restrict__ Wt,
                         const float* __restrict__ bias, float* __restrict__ out) {
    __shared__ u16 As[2][64 * 32];    // 2 x 4 KB
    __shared__ u16 Bs[2][128 * 32];   // 2 x 8 KB -> 24 KB total
    const int n0 = blockIdx.x * 128;
    const int m0 = blockIdx.y * 64;
    const int t = threadIdx.x;
    const int lane = t & 63, w = t >> 6, quad = lane >> 4, lm = lane & 15;
    const int wm = (w & 1) * 32, wn = (w >> 1) * 64;

    f32x4 acc[2][4] = {};

    auto stage = [&](int k0, int buf) {
        stage16(A, m0, k0, As[buf], w * 16, lane);
        stage16(Wt, n0, k0, Bs[buf], w * 32, lane);
        stage16(Wt, n0, k0, Bs[buf], w * 32 + 16, lane);
    };

    stage(0, 0);
    __syncthreads();
    for (int k0 = 0; k0 < 1024; k0 += 32) {
        const int cur = (k0 >> 5) & 1;
        if (k0 + 32 < 1024) stage(k0 + 32, cur ^ 1);
        short8 af[2], bf[4];
        const int sw = (quad ^ (lm & 3)) * 8;
#pragma unroll
        for (int mi = 0; mi < 2; mi++)
            af[mi] = *(const short8*)(&As[cur][(wm + mi * 16 + lm) * 32] + sw);
#pragma unroll
        for (int ni = 0; ni < 4; ni++)
            bf[ni] = *(const short8*)(&Bs[cur][(wn + ni * 16 + lm) * 32] + sw);
#pragma unroll
        for (int mi = 0; mi < 2; mi++)
#pragma unroll
            for (int ni = 0; ni < 4; ni++)
                acc[mi][ni] = __builtin_amdgcn_mfma_f32_16x16x32_bf16(
                    af[mi], bf[ni], acc[mi][ni], 0, 0, 0);
        __syncthreads();
    }

#pragma unroll
    for (int ni = 0; ni < 4; ni++) {
        const int n = n0 + wn + ni * 16 + lm;
        const float bv_ = bias[n];
#pragma unroll
        for (int mi = 0; mi < 2; mi++)
#pragma unroll
            for (int r = 0; r < 4; r++) {
                const int m = m0 + wm + mi * 16 + quad * 4 + r;
                out[(size_t)m * 1024 + n] = acc[mi][ni][r] + bv_;
            }
    }
}

// ---------------- flash attention, causal (R15) ---------------------------
// Grid 1024 blocks, 256 thr = 4 waves; wave owns 16 q-rows; Q-tile 64,
// K-tile 64, double-buffered LDS via global_load_lds, XOR swizzle.
// LDS exactly 40960 B -> 4 blocks/CU; balanced qt mapping -> 66 steps/CU.
__launch_bounds__(256, 4)
__global__ void attn_kernel(const u16* __restrict__ Q, const u16* __restrict__ K,
                            const u16* __restrict__ Vt, u16* __restrict__ Out) {
    __shared__ u16 Ks[2][64 * 64];    // 2 x 8 KB, swizzled
    __shared__ u16 Vs[2][64 * 64];    // 2 x 8 KB, swizzled
    __shared__ u16 Ps[4 * 16 * 64];   // 8 KB, XOR-chunk swizzled -> 40960 B
    const int t = threadIdx.x;
    const int lane = t & 63, w = t >> 6, quad = lane >> 4, lm = lane & 15;
    // balanced static schedule: CU c's 4 resident blocks sum to 66 steps
    const int i = blockIdx.x >> 5;
    const int qt = (i < 16) ? (31 - i) : (i - 16);
    const int bh = blockIdx.x & 31;
    const int b = bh >> 4, h = bh & 15;
    const size_t base = (size_t)(b * NH + h) * SEQ * HD;
    const u16* Qg = Q + base;
    const u16* Kg = K + base;
    const u16* Vg = Vt + base;
    const int q0 = qt * 64 + w * 16;
    const int nk = qt + 1;   // number of 64-key steps

    short8 qf[2];
#pragma unroll
    for (int kk = 0; kk < 2; kk++)
        qf[kk] = *(const short8*)(Qg + (size_t)(q0 + lm) * HD + kk * 32 + quad * 8);

    f32x4 oacc[4] = {};
    f32x4 lacc = {};
    short8 ones;
#pragma unroll
    for (int j = 0; j < 8; j++) ones[j] = (short)0x3F80;   // bf16 1.0

    u16* Pw = Ps + w * 16 * 64;

    const int srow = (lane >> 3);          // 0..7 within 8-row group
    const int schunk = (lane & 7) ^ srow;  // source logical chunk (r&7 == srow)
    auto stage_kv = [&](int kt, int buf) {
#pragma unroll
        for (int j = 0; j < 2; j++) {
            const int row = w * 16 + j * 8 + srow;
            const u16* gk = Kg + (size_t)(kt * 64 + row) * HD + schunk * 8;
            const u16* gv = Vg + (size_t)row * SEQ + kt * 64 + schunk * 8;
            __builtin_amdgcn_global_load_lds((gu32*)gk, (lu32*)(&Ks[buf][(w * 16 + j * 8) * 64]), 16, 0, 0);
            __builtin_amdgcn_global_load_lds((gu32*)gv, (lu32*)(&Vs[buf][(w * 16 + j * 8) * 64]), 16, 0, 0);
        }
    };

    auto compute_step = [&](const u16* Kc, const u16* Vc, int kt_) {
        f32x4 sacc[4];
#pragma unroll
        for (int n = 0; n < 4; n++) {
            const int r = n * 16 + lm;
            const u16* rowp = Kc + r * 64;
            short8 kf0 = *(const short8*)(rowp + ((quad ^ (r & 7)) * 8));
            short8 kf1 = *(const short8*)(rowp + (((quad + 4) ^ (r & 7)) * 8));
            f32x4 a = {};
            a = __builtin_amdgcn_mfma_f32_16x16x32_bf16(qf[0], kf0, a, 0, 0, 0);
            a = __builtin_amdgcn_mfma_f32_16x16x32_bf16(qf[1], kf1, a, 0, 0, 0);
            sacc[n] = a;
        }
        if (kt_ == qt) {   // causal mask, diagonal tile only
#pragma unroll
            for (int n = 0; n < 4; n++)
#pragma unroll
                for (int r = 0; r < 4; r++)
                    if (n * 16 + lm > w * 16 + quad * 4 + r)
                        sacc[n][r] = -__builtin_inff();
        }
        // P[q][key] at Pw[q*64 + ((key>>3)^(q&7))*8 + (key&7)]
        {
            const int qloc = quad * 4;     // + r
#pragma unroll
            for (int n = 0; n < 4; n++)
#pragma unroll
                for (int r = 0; r < 4; r++) {
                    const int q = qloc + r;
                    Pw[q * 64 + (((n * 2 + (lm >> 3)) ^ (q & 7)) * 8) + (lm & 7)] =
                        (u16)(__float_as_uint(exp2f(sacc[n][r])) >> 16);
                }
        }
        short8 pf[2];
#pragma unroll
        for (int k4 = 0; k4 < 2; k4++)
            pf[k4] = *(const short8*)(Pw + lm * 64 + (((k4 * 4 + quad) ^ (lm & 7)) * 8));
#pragma unroll
        for (int n = 0; n < 4; n++) {
            const int r = n * 16 + lm;
            const u16* rowp = Vc + r * 64;
#pragma unroll
            for (int k4 = 0; k4 < 2; k4++) {
                short8 vf = *(const short8*)(rowp + (((k4 * 4 + quad) ^ (r & 7)) * 8));
                oacc[n] = __builtin_amdgcn_mfma_f32_16x16x32_bf16(pf[k4], vf, oacc[n], 0, 0, 0);
            }
        }
#pragma unroll
        for (int k4 = 0; k4 < 2; k4++)
            lacc = __builtin_amdgcn_mfma_f32_16x16x32_bf16(pf[k4], ones, lacc, 0, 0, 0);
    };

    stage_kv(0, 0);
    __syncthreads();

    for (int kt = 0; kt < nk; kt++) {
        const int cur = kt & 1;
        if (kt + 1 < nk) stage_kv(kt + 1, cur ^ 1);   // async, no VGPRs held
        compute_step(Ks[cur], Vs[cur], kt);
        __syncthreads();   // drains vmcnt (tile kt+1 landed) + guards buf reuse
    }

    float inv[4];
#pragma unroll
    for (int r = 0; r < 4; r++) inv[r] = 1.0f / lacc[r];
#pragma unroll
    for (int n = 0; n < 4; n++)
#pragma unroll
        for (int r = 0; r < 4; r++) {
            const int qq = q0 + quad * 4 + r;
            Out[(size_t)(b * SEQ + qq) * HIDDEN + h * HD + n * 16 + lm] =
                f2bf(oacc[n][r] * inv[r]);
        }
}

// ---------------- launcher ------------------------------------------------
extern "C" void kernel_launch(void* const* d_in, const int* in_sizes, int n_in,
                              void* d_out, int out_size, void* d_ws, size_t ws_size,
                              hipStream_t stream) {
    const float* x  = (const float*)d_in[0];
    const float* Wq = (const float*)d_in[1];
    const float* bq = (const float*)d_in[2];
    const float* Wk = (const float*)d_in[3];
    const float* bk = (const float*)d_in[4];
    const float* Wv = (const float*)d_in[5];
    const float* bv = (const float*)d_in[6];
    const float* Wo = (const float*)d_in[7];
    const float* bo = (const float*)d_in[8];
    float* out = (float*)d_out;

    char* ws = (char*)d_ws;
    const size_t SZ_X = (size_t)4096 * 1024 * 2;   // 8 MB bf16
    const size_t SZ_W = (size_t)1024 * 1024 * 2;   // 2 MB bf16
    u16* xb    = (u16*)(ws);
    u16* wqb   = (u16*)(ws + SZ_X);
    u16* wkb   = (u16*)(ws + SZ_X + SZ_W);
    u16* wvb   = (u16*)(ws + SZ_X + 2 * SZ_W);
    u16* wob   = (u16*)(ws + SZ_X + 3 * SZ_W);
    u16* Qb    = (u16*)(ws + SZ_X + 4 * SZ_W);
    u16* Kb    = (u16*)(ws + 2 * SZ_X + 4 * SZ_W);
    u16* Vtb   = (u16*)(ws + 3 * SZ_X + 4 * SZ_W);
    u16* attnb = (u16*)(ws + 4 * SZ_X + 4 * SZ_W);

    cvt_all<<<4096, 256, 0, stream>>>(x, Wq, Wk, Wv, Wo, xb, wqb, wkb, wvb, wob);
    gemm_qkv<<<dim3(24, 32), 256, 0, stream>>>(xb, wqb, wkb, wvb, bq, bk, bv, Qb, Kb, Vtb);
    attn_kernel<<<BATCH * NH * (SEQ / 64), 256, 0, stream>>>(Qb, Kb, Vtb, attnb);
    gemm_out<<<dim3(8, 64), 256, 0, stream>>>(attnb, wob, bo, out);
}

// Round 3
// 189.484 us; speedup vs baseline: 1.2360x; 1.0184x over previous
//
#include <hip/hip_runtime.h>
#include <stdint.h>

// MultiHeadAttention: B=2, S=2048, HIDDEN=1024, NH=16, HD=64, causal.
// R16: attn only. (a) QK^T operands swapped: mfma(kf,qf) -> C[key][q], so
//      each lane holds 4 CONSECUTIVE keys for one q -> P-write becomes
//      4 x ds_write_b64 (packed) instead of 16 x ds_write_b16 + 16 shifts
//      (shortens the per-step serial chain; R15 showed chain-bound:
//      MfmaUtil 15.5, VALU 37.5, conflicts 0, HBM 5%).
//      (b) s_setprio(1) around the two MFMA clusters (T5, attn-positive).
//      R15 carried: Ps XOR swizzle (40960 B LDS), balanced 66-step/CU map.
// MFMA 16x16x32 bf16 layouts (HW-verified):
//   A/B frag: lane holds row[m=lane&15][k=(lane>>4)*8 + j]
//   C/D:      row=(lane>>4)*4+reg, col=lane&15

#define HIDDEN 1024
#define NH 16
#define HD 64
#define BATCH 2
#define SEQ 2048

typedef unsigned short u16;
typedef unsigned int u32;
typedef __attribute__((ext_vector_type(8))) short short8;   // 8 bf16
typedef __attribute__((ext_vector_type(4))) float f32x4;

typedef const __attribute__((address_space(1))) u32 gu32;
typedef __attribute__((address_space(3))) u32 lu32;

__device__ __forceinline__ u16 f2bf(float f) {
    u32 u = __float_as_uint(f);
    return (u16)((u + 0x7FFFu + ((u >> 16) & 1u)) >> 16);   // RNE
}

// ---------------- fused fp32 -> bf16 conversion (x + 4 weights) -----------
__global__ void cvt_all(const float* __restrict__ x, const float* __restrict__ Wq,
                        const float* __restrict__ Wk, const float* __restrict__ Wv,
                        const float* __restrict__ Wo, u16* __restrict__ xb,
                        u16* __restrict__ wqb, u16* __restrict__ wkb,
                        u16* __restrict__ wvb, u16* __restrict__ wob) {
    const int blk = blockIdx.x;
    const float* src; u16* dst; int base;
    if (blk < 2048)      { src = x;  dst = xb;  base = blk; }
    else if (blk < 2560) { src = Wq; dst = wqb; base = blk - 2048; }
    else if (blk < 3072) { src = Wk; dst = wkb; base = blk - 2560; }
    else if (blk < 3584) { src = Wv; dst = wvb; base = blk - 3072; }
    else                 { src = Wo; dst = wob; base = blk - 3584; }
    const int i = base * 256 + threadIdx.x;
    float4 a = ((const float4*)src)[2 * i];
    float4 b = ((const float4*)src)[2 * i + 1];
    union { u16 h[8]; uint4 v; } o;
    o.h[0] = f2bf(a.x); o.h[1] = f2bf(a.y); o.h[2] = f2bf(a.z); o.h[3] = f2bf(a.w);
    o.h[4] = f2bf(b.x); o.h[5] = f2bf(b.y); o.h[6] = f2bf(b.z); o.h[7] = f2bf(b.w);
    ((uint4*)dst)[i] = o.v;
}

// ---- async stage: 16 rows x 32 cols (64 B/row) per call, XOR-4 swizzle ----
__device__ __forceinline__ void stage16(const u16* __restrict__ G, int grow0,
                                        int k0, u16* lds, int rbase, int lane) {
    const int sr = lane >> 2;
    const int lc = (lane & 3) ^ (sr & 3);
    const u16* g = G + (size_t)(grow0 + rbase + sr) * 1024 + k0 + lc * 8;
    __builtin_amdgcn_global_load_lds((gu32*)g, (lu32*)(lds + rbase * 32), 16, 0, 0);
}

// ---------------- fused QKV projection ------------------------------------
// grid (24, 32). Q/K -> [B,H,S,D] direct; V -> [B,H,D,S] via LDS transpose.
__launch_bounds__(256, 3)
__global__ void gemm_qkv(const u16* __restrict__ A, const u16* __restrict__ Wqb,
                         const u16* __restrict__ Wkb, const u16* __restrict__ Wvb,
                         const float* __restrict__ bq, const float* __restrict__ bk,
                         const float* __restrict__ bv, u16* __restrict__ Qo,
                         u16* __restrict__ Ko, u16* __restrict__ Vo) {
    __shared__ u16 As[2][128 * 32];   // 2 x 8 KB
    __shared__ u16 Bs[2][128 * 32];   // 2 x 8 KB -> 32 KB total
    const int which = blockIdx.x >> 3;
    const int n0 = (blockIdx.x & 7) * 128;
    const int m0 = blockIdx.y * 128;
    const u16* Wt = (which == 0) ? Wqb : (which == 1) ? Wkb : Wvb;
    const float* bias = (which == 0) ? bq : (which == 1) ? bk : bv;
    u16* out = (which == 0) ? Qo : (which == 1) ? Ko : Vo;
    const float oscale = (which == 0) ? 0.18033688011112042f : 1.0f;  // log2e/8
    const int t = threadIdx.x;
    const int lane = t & 63, w = t >> 6, quad = lane >> 4, lm = lane & 15;
    const int wm = (w & 1) * 64, wn = (w >> 1) * 64;

    f32x4 acc[4][4] = {};

    auto stage = [&](int k0, int buf) {
        stage16(A, m0, k0, As[buf], w * 32, lane);
        stage16(A, m0, k0, As[buf], w * 32 + 16, lane);
        stage16(Wt, n0, k0, Bs[buf], w * 32, lane);
        stage16(Wt, n0, k0, Bs[buf], w * 32 + 16, lane);
    };

    stage(0, 0);
    __syncthreads();
    for (int k0 = 0; k0 < 1024; k0 += 32) {
        const int cur = (k0 >> 5) & 1;
        if (k0 + 32 < 1024) stage(k0 + 32, cur ^ 1);
        short8 af[4], bf[4];
        const int sw = (quad ^ (lm & 3)) * 8;   // swizzled slot offset (elems)
#pragma unroll
        for (int mi = 0; mi < 4; mi++)
            af[mi] = *(const short8*)(&As[cur][(wm + mi * 16 + lm) * 32] + sw);
#pragma unroll
        for (int ni = 0; ni < 4; ni++)
            bf[ni] = *(const short8*)(&Bs[cur][(wn + ni * 16 + lm) * 32] + sw);
#pragma unroll
        for (int mi = 0; mi < 4; mi++)
#pragma unroll
            for (int ni = 0; ni < 4; ni++)
                acc[mi][ni] = __builtin_amdgcn_mfma_f32_16x16x32_bf16(
                    af[mi], bf[ni], acc[mi][ni], 0, 0, 0);
        __syncthreads();   // drains vmcnt (next tile landed) + guards buf reuse
    }

    if (which == 2) {
        // V: per-wave LDS transpose -> coalesced [B,H,D,S] stores.
        u16* Tw = ((w < 2) ? (u16*)As : (u16*)Bs) + (w & 1) * 4096;
#pragma unroll
        for (int ni = 0; ni < 4; ni++) {
            const int n_loc = ni * 16 + lm;
            const float bv_ = bias[n0 + wn + n_loc];
#pragma unroll
            for (int mi = 0; mi < 4; mi++)
#pragma unroll
                for (int r = 0; r < 4; r++) {
                    const int m_loc = mi * 16 + quad * 4 + r;
                    Tw[n_loc * 64 + (((m_loc >> 3) ^ (n_loc & 7)) * 8) + (m_loc & 7)] =
                        f2bf(acc[mi][ni][r] + bv_);
                }
        }
        const int hh = (n0 + wn) >> 6;
        const int mg = m0 + wm;             // 64-aligned, never straddles batch
        const int bb = mg >> 11, s0 = mg & 2047;
        u16* outp = out + ((size_t)(bb * NH + hh) * HD) * SEQ;
        const int cm = lane & 7;            // logical m-chunk (8 elems)
#pragma unroll
        for (int i = 0; i < 8; i++) {
            const int n_loc = i * 8 + (lane >> 3);   // d
            short8 v = *(const short8*)(Tw + n_loc * 64 + ((cm ^ (n_loc & 7)) * 8));
            *(short8*)(outp + (size_t)n_loc * SEQ + s0 + cm * 8) = v;
        }
    } else {
#pragma unroll
        for (int ni = 0; ni < 4; ni++) {
            const int n = n0 + wn + ni * 16 + lm;
            const float bv_ = bias[n];
            const int h = n >> 6, d = n & 63;
#pragma unroll
            for (int mi = 0; mi < 4; mi++)
#pragma unroll
                for (int r = 0; r < 4; r++) {
                    const int m = m0 + wm + mi * 16 + quad * 4 + r;
                    const int b = m >> 11, s = m & 2047;
                    out[(((size_t)(b * NH + h) * SEQ + s) * HD) + d] =
                        f2bf((acc[mi][ni][r] + bv_) * oscale);
                }
        }
    }
}

// ---------------- output projection (R10, unchanged) ----------------------
__launch_bounds__(256, 2)
__global__ void gemm_out(const u16* __restrict__ A, const u16* __restrict__ Wt,
                         const float* __restrict__ bias, float* __restrict__ out) {
    __shared__ u16 As[2][64 * 32];    // 2 x 4 KB
    __shared__ u16 Bs[2][128 * 32];   // 2 x 8 KB -> 24 KB total
    const int n0 = blockIdx.x * 128;
    const int m0 = blockIdx.y * 64;
    const int t = threadIdx.x;
    const int lane = t & 63, w = t >> 6, quad = lane >> 4, lm = lane & 15;
    const int wm = (w & 1) * 32, wn = (w >> 1) * 64;

    f32x4 acc[2][4] = {};

    auto stage = [&](int k0, int buf) {
        stage16(A, m0, k0, As[buf], w * 16, lane);
        stage16(Wt, n0, k0, Bs[buf], w * 32, lane);
        stage16(Wt, n0, k0, Bs[buf], w * 32 + 16, lane);
    };

    stage(0, 0);
    __syncthreads();
    for (int k0 = 0; k0 < 1024; k0 += 32) {
        const int cur = (k0 >> 5) & 1;
        if (k0 + 32 < 1024) stage(k0 + 32, cur ^ 1);
        short8 af[2], bf[4];
        const int sw = (quad ^ (lm & 3)) * 8;
#pragma unroll
        for (int mi = 0; mi < 2; mi++)
            af[mi] = *(const short8*)(&As[cur][(wm + mi * 16 + lm) * 32] + sw);
#pragma unroll
        for (int ni = 0; ni < 4; ni++)
            bf[ni] = *(const short8*)(&Bs[cur][(wn + ni * 16 + lm) * 32] + sw);
#pragma unroll
        for (int mi = 0; mi < 2; mi++)
#pragma unroll
            for (int ni = 0; ni < 4; ni++)
                acc[mi][ni] = __builtin_amdgcn_mfma_f32_16x16x32_bf16(
                    af[mi], bf[ni], acc[mi][ni], 0, 0, 0);
        __syncthreads();
    }

#pragma unroll
    for (int ni = 0; ni < 4; ni++) {
        const int n = n0 + wn + ni * 16 + lm;
        const float bv_ = bias[n];
#pragma unroll
        for (int mi = 0; mi < 2; mi++)
#pragma unroll
            for (int r = 0; r < 4; r++) {
                const int m = m0 + wm + mi * 16 + quad * 4 + r;
                out[(size_t)m * 1024 + n] = acc[mi][ni][r] + bv_;
            }
    }
}

// ---------------- flash attention, causal (R16) ---------------------------
// Grid 1024 blocks, 256 thr = 4 waves; wave owns 16 q-rows; Q-tile 64,
// K-tile 64, double-buffered LDS via global_load_lds, XOR swizzle.
// LDS 40960 B; balanced qt mapping -> 66 steps/CU.
// Swapped QK^T: mfma(kf,qf) -> C[key][q]; lane holds keys n*16+quad*4+{0..3}
// for q=lm -> packed ds_write_b64 P stores.
__launch_bounds__(256, 4)
__global__ void attn_kernel(const u16* __restrict__ Q, const u16* __restrict__ K,
                            const u16* __restrict__ Vt, u16* __restrict__ Out) {
    __shared__ u16 Ks[2][64 * 64];    // 2 x 8 KB, swizzled
    __shared__ u16 Vs[2][64 * 64];    // 2 x 8 KB, swizzled
    __shared__ u16 Ps[4 * 16 * 64];   // 8 KB, XOR-chunk swizzled -> 40960 B
    const int t = threadIdx.x;
    const int lane = t & 63, w = t >> 6, quad = lane >> 4, lm = lane & 15;
    // balanced static schedule: CU c's 4 resident blocks sum to 66 steps
    const int i = blockIdx.x >> 5;
    const int qt = (i < 16) ? (31 - i) : (i - 16);
    const int bh = blockIdx.x & 31;
    const int b = bh >> 4, h = bh & 15;
    const size_t base = (size_t)(b * NH + h) * SEQ * HD;
    const u16* Qg = Q + base;
    const u16* Kg = K + base;
    const u16* Vg = Vt + base;
    const int q0 = qt * 64 + w * 16;
    const int nk = qt + 1;   // number of 64-key steps

    short8 qf[2];
#pragma unroll
    for (int kk = 0; kk < 2; kk++)
        qf[kk] = *(const short8*)(Qg + (size_t)(q0 + lm) * HD + kk * 32 + quad * 8);

    f32x4 oacc[4] = {};
    f32x4 lacc = {};
    short8 ones;
#pragma unroll
    for (int j = 0; j < 8; j++) ones[j] = (short)0x3F80;   // bf16 1.0

    u16* Pw = Ps + w * 16 * 64;

    const int srow = (lane >> 3);          // 0..7 within 8-row group
    const int schunk = (lane & 7) ^ srow;  // source logical chunk (r&7 == srow)
    auto stage_kv = [&](int kt, int buf) {
#pragma unroll
        for (int j = 0; j < 2; j++) {
            const int row = w * 16 + j * 8 + srow;
            const u16* gk = Kg + (size_t)(kt * 64 + row) * HD + schunk * 8;
            const u16* gv = Vg + (size_t)row * SEQ + kt * 64 + schunk * 8;
            __builtin_amdgcn_global_load_lds((gu32*)gk, (lu32*)(&Ks[buf][(w * 16 + j * 8) * 64]), 16, 0, 0);
            __builtin_amdgcn_global_load_lds((gu32*)gv, (lu32*)(&Vs[buf][(w * 16 + j * 8) * 64]), 16, 0, 0);
        }
    };

    auto compute_step = [&](const u16* Kc, const u16* Vc, int kt_) {
        // Swapped QK^T: sacc[n] = C[key_local][q], key = n*16 + quad*4 + reg,
        // q = q0 + lm. kf as A-frag, qf as B-frag (identical frag layouts).
        f32x4 sacc[4];
        __builtin_amdgcn_s_setprio(1);
#pragma unroll
        for (int n = 0; n < 4; n++) {
            const int r = n * 16 + lm;
            const u16* rowp = Kc + r * 64;
            short8 kf0 = *(const short8*)(rowp + ((quad ^ (r & 7)) * 8));
            short8 kf1 = *(const short8*)(rowp + (((quad + 4) ^ (r & 7)) * 8));
            f32x4 a = {};
            a = __builtin_amdgcn_mfma_f32_16x16x32_bf16(kf0, qf[0], a, 0, 0, 0);
            a = __builtin_amdgcn_mfma_f32_16x16x32_bf16(kf1, qf[1], a, 0, 0, 0);
            sacc[n] = a;
        }
        __builtin_amdgcn_s_setprio(0);
        if (kt_ == qt) {   // causal mask, diagonal tile only: key > q
#pragma unroll
            for (int n = 0; n < 4; n++)
#pragma unroll
                for (int r = 0; r < 4; r++)
                    if (n * 16 + quad * 4 + r > w * 16 + lm)
                        sacc[n][r] = -__builtin_inff();
        }
        // P[q][key] at Pw[q*64 + ((key>>3)^(q&7))*8 + (key&7)].
        // Lane's 4 keys (n*16+quad*4+r, r=0..3) are consecutive -> one b64.
        {
            const int q = lm;
            const int co = (quad & 1) * 4;             // in-chunk offset
#pragma unroll
            for (int n = 0; n < 4; n++) {
                u32 e0 = __float_as_uint(exp2f(sacc[n][0]));
                u32 e1 = __float_as_uint(exp2f(sacc[n][1]));
                u32 e2 = __float_as_uint(exp2f(sacc[n][2]));
                u32 e3 = __float_as_uint(exp2f(sacc[n][3]));
                uint2 pk;
                pk.x = (e0 >> 16) | (e1 & 0xFFFF0000u);
                pk.y = (e2 >> 16) | (e3 & 0xFFFF0000u);
                const int chunk = (n * 2 + (quad >> 1)) ^ (q & 7);
                *(uint2*)(Pw + q * 64 + chunk * 8 + co) = pk;
            }
        }
        short8 pf[2];
#pragma unroll
        for (int k4 = 0; k4 < 2; k4++)
            pf[k4] = *(const short8*)(Pw + lm * 64 + (((k4 * 4 + quad) ^ (lm & 7)) * 8));
        __builtin_amdgcn_s_setprio(1);
#pragma unroll
        for (int n = 0; n < 4; n++) {
            const int r = n * 16 + lm;
            const u16* rowp = Vc + r * 64;
#pragma unroll
            for (int k4 = 0; k4 < 2; k4++) {
                short8 vf = *(const short8*)(rowp + (((k4 * 4 + quad) ^ (r & 7)) * 8));
                oacc[n] = __builtin_amdgcn_mfma_f32_16x16x32_bf16(pf[k4], vf, oacc[n], 0, 0, 0);
            }
        }
#pragma unroll
        for (int k4 = 0; k4 < 2; k4++)
            lacc = __builtin_amdgcn_mfma_f32_16x16x32_bf16(pf[k4], ones, lacc, 0, 0, 0);
        __builtin_amdgcn_s_setprio(0);
    };

    stage_kv(0, 0);
    __syncthreads();

    for (int kt = 0; kt < nk; kt++) {
        const int cur = kt & 1;
        if (kt + 1 < nk) stage_kv(kt + 1, cur ^ 1);   // async, no VGPRs held
        compute_step(Ks[cur], Vs[cur], kt);
        __syncthreads();   // drains vmcnt (tile kt+1 landed) + guards buf reuse
    }

    float inv[4];
#pragma unroll
    for (int r = 0; r < 4; r++) inv[r] = 1.0f / lacc[r];
#pragma unroll
    for (int n = 0; n < 4; n++)
#pragma unroll
        for (int r = 0; r < 4; r++) {
            const int qq = q0 + quad * 4 + r;
            Out[(size_t)(b * SEQ + qq) * HIDDEN + h * HD + n * 16 + lm] =
                f2bf(oacc[n][r] * inv[r]);
        }
}

// ---------------- launcher ------------------------------------------------
extern "C" void kernel_launch(void* const* d_in, const int* in_sizes, int n_in,
                              void* d_out, int out_size, void* d_ws, size_t ws_size,
                              hipStream_t stream) {
    const float* x  = (const float*)d_in[0];
    const float* Wq = (const float*)d_in[1];
    const float* bq = (const float*)d_in[2];
    const float* Wk = (const float*)d_in[3];
    const float* bk = (const float*)d_in[4];
    const float* Wv = (const float*)d_in[5];
    const float* bv = (const float*)d_in[6];
    const float* Wo = (const float*)d_in[7];
    const float* bo = (const float*)d_in[8];
    float* out = (float*)d_out;

    char* ws = (char*)d_ws;
    const size_t SZ_X = (size_t)4096 * 1024 * 2;   // 8 MB bf16
    const size_t SZ_W = (size_t)1024 * 1024 * 2;   // 2 MB bf16
    u16* xb    = (u16*)(ws);
    u16* wqb   = (u16*)(ws + SZ_X);
    u16* wkb   = (u16*)(ws + SZ_X + SZ_W);
    u16* wvb   = (u16*)(ws + SZ_X + 2 * SZ_W);
    u16* wob   = (u16*)(ws + SZ_X + 3 * SZ_W);
    u16* Qb    = (u16*)(ws + SZ_X + 4 * SZ_W);
    u16* Kb    = (u16*)(ws + 2 * SZ_X + 4 * SZ_W);
    u16* Vtb   = (u16*)(ws + 3 * SZ_X + 4 * SZ_W);
    u16* attnb = (u16*)(ws + 4 * SZ_X + 4 * SZ_W);

    cvt_all<<<4096, 256, 0, stream>>>(x, Wq, Wk, Wv, Wo, xb, wqb, wkb, wvb, wob);
    gemm_qkv<<<dim3(24, 32), 256, 0, stream>>>(xb, wqb, wkb, wvb, bq, bk, bv, Qb, Kb, Vtb);
    attn_kernel<<<BATCH * NH * (SEQ / 64), 256, 0, stream>>>(Qb, Kb, Vtb, attnb);
    gemm_out<<<dim3(8, 64), 256, 0, stream>>>(attnb, wob, bo, out);
}

// Round 4
// 187.286 us; speedup vs baseline: 1.2505x; 1.0117x over previous
//
#include <hip/hip_runtime.h>
#include <stdint.h>

// MultiHeadAttention: B=2, S=2048, HIDDEN=1024, NH=16, HD=64, causal.
// R17: attn only. (a) equal-length blocks: each block does q-tiles {31-p, p}
//      sequentially -> 512 blocks x exactly 33 steps (R16 showed time-imbalance:
//      avg residency 2.3 blocks/CU with a 1-block tail). (b) software pipeline:
//      QK-MFMA(kt+1) placed inside P-write->P-read lgkm window of step kt.
//      (c) P row = 16 8B slots, physical slot = l^lm -> conflict-free b64
//      write AND read (R16 had 1.08M conflicts, 2-way per quarter-wave).
//      (d) v_cvt_pk_bf16_f32 packing (saves ~16 VALU/step).
// MFMA 16x16x32 bf16 layouts (HW-verified):
//   A/B frag: lane holds row[m=lane&15][k=(lane>>4)*8 + j]
//   C/D:      row=(lane>>4)*4+reg, col=lane&15
// Swapped QK^T: mfma(kf,qf) -> C[key][q]; lane holds keys n*16+quad*4+{0..3}
// for q=lm -> keys 4-aligned -> slot-granular (8B) P stores.

#define HIDDEN 1024
#define NH 16
#define HD 64
#define BATCH 2
#define SEQ 2048

typedef unsigned short u16;
typedef unsigned int u32;
typedef __attribute__((ext_vector_type(8))) short short8;   // 8 bf16
typedef __attribute__((ext_vector_type(4))) float f32x4;

typedef const __attribute__((address_space(1))) u32 gu32;
typedef __attribute__((address_space(3))) u32 lu32;

__device__ __forceinline__ u16 f2bf(float f) {
    u32 u = __float_as_uint(f);
    return (u16)((u + 0x7FFFu + ((u >> 16) & 1u)) >> 16);   // RNE
}

// ---------------- fused fp32 -> bf16 conversion (x + 4 weights) -----------
__global__ void cvt_all(const float* __restrict__ x, const float* __restrict__ Wq,
                        const float* __restrict__ Wk, const float* __restrict__ Wv,
                        const float* __restrict__ Wo, u16* __restrict__ xb,
                        u16* __restrict__ wqb, u16* __restrict__ wkb,
                        u16* __restrict__ wvb, u16* __restrict__ wob) {
    const int blk = blockIdx.x;
    const float* src; u16* dst; int base;
    if (blk < 2048)      { src = x;  dst = xb;  base = blk; }
    else if (blk < 2560) { src = Wq; dst = wqb; base = blk - 2048; }
    else if (blk < 3072) { src = Wk; dst = wkb; base = blk - 2560; }
    else if (blk < 3584) { src = Wv; dst = wvb; base = blk - 3072; }
    else                 { src = Wo; dst = wob; base = blk - 3584; }
    const int i = base * 256 + threadIdx.x;
    float4 a = ((const float4*)src)[2 * i];
    float4 b = ((const float4*)src)[2 * i + 1];
    union { u16 h[8]; uint4 v; } o;
    o.h[0] = f2bf(a.x); o.h[1] = f2bf(a.y); o.h[2] = f2bf(a.z); o.h[3] = f2bf(a.w);
    o.h[4] = f2bf(b.x); o.h[5] = f2bf(b.y); o.h[6] = f2bf(b.z); o.h[7] = f2bf(b.w);
    ((uint4*)dst)[i] = o.v;
}

// ---- async stage: 16 rows x 32 cols (64 B/row) per call, XOR-4 swizzle ----
__device__ __forceinline__ void stage16(const u16* __restrict__ G, int grow0,
                                        int k0, u16* lds, int rbase, int lane) {
    const int sr = lane >> 2;
    const int lc = (lane & 3) ^ (sr & 3);
    const u16* g = G + (size_t)(grow0 + rbase + sr) * 1024 + k0 + lc * 8;
    __builtin_amdgcn_global_load_lds((gu32*)g, (lu32*)(lds + rbase * 32), 16, 0, 0);
}

// ---------------- fused QKV projection ------------------------------------
// grid (24, 32). Q/K -> [B,H,S,D] direct; V -> [B,H,D,S] via LDS transpose.
__launch_bounds__(256, 3)
__global__ void gemm_qkv(const u16* __restrict__ A, const u16* __restrict__ Wqb,
                         const u16* __restrict__ Wkb, const u16* __restrict__ Wvb,
                         const float* __restrict__ bq, const float* __restrict__ bk,
                         const float* __restrict__ bv, u16* __restrict__ Qo,
                         u16* __restrict__ Ko, u16* __restrict__ Vo) {
    __shared__ u16 As[2][128 * 32];   // 2 x 8 KB
    __shared__ u16 Bs[2][128 * 32];   // 2 x 8 KB -> 32 KB total
    const int which = blockIdx.x >> 3;
    const int n0 = (blockIdx.x & 7) * 128;
    const int m0 = blockIdx.y * 128;
    const u16* Wt = (which == 0) ? Wqb : (which == 1) ? Wkb : Wvb;
    const float* bias = (which == 0) ? bq : (which == 1) ? bk : bv;
    u16* out = (which == 0) ? Qo : (which == 1) ? Ko : Vo;
    const float oscale = (which == 0) ? 0.18033688011112042f : 1.0f;  // log2e/8
    const int t = threadIdx.x;
    const int lane = t & 63, w = t >> 6, quad = lane >> 4, lm = lane & 15;
    const int wm = (w & 1) * 64, wn = (w >> 1) * 64;

    f32x4 acc[4][4] = {};

    auto stage = [&](int k0, int buf) {
        stage16(A, m0, k0, As[buf], w * 32, lane);
        stage16(A, m0, k0, As[buf], w * 32 + 16, lane);
        stage16(Wt, n0, k0, Bs[buf], w * 32, lane);
        stage16(Wt, n0, k0, Bs[buf], w * 32 + 16, lane);
    };

    stage(0, 0);
    __syncthreads();
    for (int k0 = 0; k0 < 1024; k0 += 32) {
        const int cur = (k0 >> 5) & 1;
        if (k0 + 32 < 1024) stage(k0 + 32, cur ^ 1);
        short8 af[4], bf[4];
        const int sw = (quad ^ (lm & 3)) * 8;   // swizzled slot offset (elems)
#pragma unroll
        for (int mi = 0; mi < 4; mi++)
            af[mi] = *(const short8*)(&As[cur][(wm + mi * 16 + lm) * 32] + sw);
#pragma unroll
        for (int ni = 0; ni < 4; ni++)
            bf[ni] = *(const short8*)(&Bs[cur][(wn + ni * 16 + lm) * 32] + sw);
#pragma unroll
        for (int mi = 0; mi < 4; mi++)
#pragma unroll
            for (int ni = 0; ni < 4; ni++)
                acc[mi][ni] = __builtin_amdgcn_mfma_f32_16x16x32_bf16(
                    af[mi], bf[ni], acc[mi][ni], 0, 0, 0);
        __syncthreads();   // drains vmcnt (next tile landed) + guards buf reuse
    }

    if (which == 2) {
        // V: per-wave LDS transpose -> coalesced [B,H,D,S] stores.
        u16* Tw = ((w < 2) ? (u16*)As : (u16*)Bs) + (w & 1) * 4096;
#pragma unroll
        for (int ni = 0; ni < 4; ni++) {
            const int n_loc = ni * 16 + lm;
            const float bv_ = bias[n0 + wn + n_loc];
#pragma unroll
            for (int mi = 0; mi < 4; mi++)
#pragma unroll
                for (int r = 0; r < 4; r++) {
                    const int m_loc = mi * 16 + quad * 4 + r;
                    Tw[n_loc * 64 + (((m_loc >> 3) ^ (n_loc & 7)) * 8) + (m_loc & 7)] =
                        f2bf(acc[mi][ni][r] + bv_);
                }
        }
        const int hh = (n0 + wn) >> 6;
        const int mg = m0 + wm;             // 64-aligned, never straddles batch
        const int bb = mg >> 11, s0 = mg & 2047;
        u16* outp = out + ((size_t)(bb * NH + hh) * HD) * SEQ;
        const int cm = lane & 7;            // logical m-chunk (8 elems)
#pragma unroll
        for (int i = 0; i < 8; i++) {
            const int n_loc = i * 8 + (lane >> 3);   // d
            short8 v = *(const short8*)(Tw + n_loc * 64 + ((cm ^ (n_loc & 7)) * 8));
            *(short8*)(outp + (size_t)n_loc * SEQ + s0 + cm * 8) = v;
        }
    } else {
#pragma unroll
        for (int ni = 0; ni < 4; ni++) {
            const int n = n0 + wn + ni * 16 + lm;
            const float bv_ = bias[n];
            const int h = n >> 6, d = n & 63;
#pragma unroll
            for (int mi = 0; mi < 4; mi++)
#pragma unroll
                for (int r = 0; r < 4; r++) {
                    const int m = m0 + wm + mi * 16 + quad * 4 + r;
                    const int b = m >> 11, s = m & 2047;
                    out[(((size_t)(b * NH + h) * SEQ + s) * HD) + d] =
                        f2bf((acc[mi][ni][r] + bv_) * oscale);
                }
        }
    }
}

// ---------------- output projection (R10, unchanged) ----------------------
__launch_bounds__(256, 2)
__global__ void gemm_out(const u16* __restrict__ A, const u16* __restrict__ Wt,
                         const float* __restrict__ bias, float* __restrict__ out) {
    __shared__ u16 As[2][64 * 32];    // 2 x 4 KB
    __shared__ u16 Bs[2][128 * 32];   // 2 x 8 KB -> 24 KB total
    const int n0 = blockIdx.x * 128;
    const int m0 = blockIdx.y * 64;
    const int t = threadIdx.x;
    const int lane = t & 63, w = t >> 6, quad = lane >> 4, lm = lane & 15;
    const int wm = (w & 1) * 32, wn = (w >> 1) * 64;

    f32x4 acc[2][4] = {};

    auto stage = [&](int k0, int buf) {
        stage16(A, m0, k0, As[buf], w * 16, lane);
        stage16(Wt, n0, k0, Bs[buf], w * 32, lane);
        stage16(Wt, n0, k0, Bs[buf], w * 32 + 16, lane);
    };

    stage(0, 0);
    __syncthreads();
    for (int k0 = 0; k0 < 1024; k0 += 32) {
        const int cur = (k0 >> 5) & 1;
        if (k0 + 32 < 1024) stage(k0 + 32, cur ^ 1);
        short8 af[2], bf[4];
        const int sw = (quad ^ (lm & 3)) * 8;
#pragma unroll
        for (int mi = 0; mi < 2; mi++)
            af[mi] = *(const short8*)(&As[cur][(wm + mi * 16 + lm) * 32] + sw);
#pragma unroll
        for (int ni = 0; ni < 4; ni++)
            bf[ni] = *(const short8*)(&Bs[cur][(wn + ni * 16 + lm) * 32] + sw);
#pragma unroll
        for (int mi = 0; mi < 2; mi++)
#pragma unroll
            for (int ni = 0; ni < 4; ni++)
                acc[mi][ni] = __builtin_amdgcn_mfma_f32_16x16x32_bf16(
                    af[mi], bf[ni], acc[mi][ni], 0, 0, 0);
        __syncthreads();
    }

#pragma unroll
    for (int ni = 0; ni < 4; ni++) {
        const int n = n0 + wn + ni * 16 + lm;
        const float bv_ = bias[n];
#pragma unroll
        for (int mi = 0; mi < 2; mi++)
#pragma unroll
            for (int r = 0; r < 4; r++) {
                const int m = m0 + wm + mi * 16 + quad * 4 + r;
                out[(size_t)m * 1024 + n] = acc[mi][ni][r] + bv_;
            }
    }
}

// ---------------- flash attention, causal (R17) ---------------------------
// 512 equal blocks (q-tile pair {31-p, p} = 33 steps each), 256 thr = 4 waves;
// wave owns 16 q-rows; K-tile 64, double-buffered via global_load_lds.
// Software-pipelined: QK(kt+1) hides P-write->P-read latency of step kt.
__launch_bounds__(256, 4)
__global__ void attn_kernel(const u16* __restrict__ Q, const u16* __restrict__ K,
                            const u16* __restrict__ Vt, u16* __restrict__ Out) {
    __shared__ u16 Ks[2][64 * 64];    // 2 x 8 KB, swizzled
    __shared__ u16 Vs[2][64 * 64];    // 2 x 8 KB, swizzled
    __shared__ u16 Ps[4 * 16 * 64];   // 8 KB, slot-XOR layout -> 40960 B total
    const int t = threadIdx.x;
    const int lane = t & 63, w = t >> 6, quad = lane >> 4, lm = lane & 15;
    const int pairIdx = blockIdx.x >> 5;       // 0..15
    const int bh = blockIdx.x & 31;
    const int b = bh >> 4, h = bh & 15;
    const size_t base = (size_t)(b * NH + h) * SEQ * HD;
    const u16* Qg = Q + base;
    const u16* Kg = K + base;
    const u16* Vg = Vt + base;

    u16* Pw = Ps + w * 16 * 64;

    const int srow = (lane >> 3);          // 0..7 within 8-row group
    const int schunk = (lane & 7) ^ srow;  // source logical chunk (r&7 == srow)
    auto stage_k = [&](int kt, int buf) {
#pragma unroll
        for (int j = 0; j < 2; j++) {
            const int row = w * 16 + j * 8 + srow;
            const u16* gk = Kg + (size_t)(kt * 64 + row) * HD + schunk * 8;
            __builtin_amdgcn_global_load_lds((gu32*)gk, (lu32*)(&Ks[buf][(w * 16 + j * 8) * 64]), 16, 0, 0);
        }
    };
    auto stage_v = [&](int kt, int buf) {
#pragma unroll
        for (int j = 0; j < 2; j++) {
            const int row = w * 16 + j * 8 + srow;
            const u16* gv = Vg + (size_t)row * SEQ + kt * 64 + schunk * 8;
            __builtin_amdgcn_global_load_lds((gu32*)gv, (lu32*)(&Vs[buf][(w * 16 + j * 8) * 64]), 16, 0, 0);
        }
    };

    short8 ones;
#pragma unroll
    for (int j = 0; j < 8; j++) ones[j] = (short)0x3F80;   // bf16 1.0

#pragma unroll 1
    for (int half = 0; half < 2; half++) {
        const int qt = half ? pairIdx : (31 - pairIdx);
        const int q0 = qt * 64 + w * 16;
        const int nk = qt + 1;

        if (half) __syncthreads();   // guard LDS reuse across tiles

        short8 qf[2];
#pragma unroll
        for (int kk = 0; kk < 2; kk++)
            qf[kk] = *(const short8*)(Qg + (size_t)(q0 + lm) * HD + kk * 32 + quad * 8);

        f32x4 oacc[4] = {};
        f32x4 lacc = {};
        f32x4 sacc[4];

        // swapped QK^T: sacc[n] = C[key][q], key = n*16+quad*4+reg, q = lm
        auto qk_tile = [&](const u16* Kc) {
            __builtin_amdgcn_s_setprio(1);
#pragma unroll
            for (int n = 0; n < 4; n++) {
                const int r = n * 16 + lm;
                const u16* rowp = Kc + r * 64;
                short8 kf0 = *(const short8*)(rowp + ((quad ^ (r & 7)) * 8));
                short8 kf1 = *(const short8*)(rowp + (((quad + 4) ^ (r & 7)) * 8));
                f32x4 a = {};
                a = __builtin_amdgcn_mfma_f32_16x16x32_bf16(kf0, qf[0], a, 0, 0, 0);
                a = __builtin_amdgcn_mfma_f32_16x16x32_bf16(kf1, qf[1], a, 0, 0, 0);
                sacc[n] = a;
            }
            __builtin_amdgcn_s_setprio(0);
        };

        // prologue: K0 -> Ks[0]; QK(0); issue K1,V0
        stage_k(0, 0);
        __syncthreads();
        if (nk > 1) stage_k(1, 1);
        stage_v(0, 0);
        qk_tile(Ks[0]);
        __syncthreads();

        for (int kt = 0; kt < nk; kt++) {
            const int kb = kt & 1;
            if (kt + 2 < nk) stage_k(kt + 2, kb);
            if (kt + 1 < nk) stage_v(kt + 1, kb ^ 1);

            // mask (diagonal step only) + exp2 + pack + P-write
            if (kt == qt) {
#pragma unroll
                for (int n = 0; n < 4; n++)
#pragma unroll
                    for (int r = 0; r < 4; r++)
                        if (n * 16 + quad * 4 + r > w * 16 + lm)
                            sacc[n][r] = -__builtin_inff();
            }
#pragma unroll
            for (int n = 0; n < 4; n++) {
                float e0 = exp2f(sacc[n][0]), e1 = exp2f(sacc[n][1]);
                float e2 = exp2f(sacc[n][2]), e3 = exp2f(sacc[n][3]);
                u32 lo, hi;
                asm("v_cvt_pk_bf16_f32 %0, %1, %2" : "=v"(lo) : "v"(e0), "v"(e1));
                asm("v_cvt_pk_bf16_f32 %0, %1, %2" : "=v"(hi) : "v"(e2), "v"(e3));
                const int pslot = (n * 4 + quad) ^ lm;     // 8B slot, conflict-free
                *(uint2*)(Pw + lm * 64 + pslot * 4) = (uint2){lo, hi};
            }
            // pf read: logical slots l0, l0+1 -> physical l^lm (b64 pair)
            short8 pf[2];
#pragma unroll
            for (int k4 = 0; k4 < 2; k4++) {
                const int l0 = k4 * 8 + quad * 2;
                uint2 a = *(const uint2*)(Pw + lm * 64 + ((l0 ^ lm) * 4));
                uint2 c = *(const uint2*)(Pw + lm * 64 + (((l0 + 1) ^ lm) * 4));
                union { short8 s; uint4 u; } m_;
                m_.u = (uint4){a.x, a.y, c.x, c.y};
                pf[k4] = m_.s;
            }
            // QK for NEXT tile (independent) -- hides the P LDS round-trip
            if (kt + 1 < nk) qk_tile(Ks[kb ^ 1]);
            // PV + row-sum
            __builtin_amdgcn_s_setprio(1);
#pragma unroll
            for (int n = 0; n < 4; n++) {
                const int r = n * 16 + lm;
                const u16* rowp = Vs[kb] + r * 64;
#pragma unroll
                for (int k4 = 0; k4 < 2; k4++) {
                    short8 vf = *(const short8*)(rowp + (((k4 * 4 + quad) ^ (r & 7)) * 8));
                    oacc[n] = __builtin_amdgcn_mfma_f32_16x16x32_bf16(pf[k4], vf, oacc[n], 0, 0, 0);
                }
            }
#pragma unroll
            for (int k4 = 0; k4 < 2; k4++)
                lacc = __builtin_amdgcn_mfma_f32_16x16x32_bf16(pf[k4], ones, lacc, 0, 0, 0);
            __builtin_amdgcn_s_setprio(0);

            if (kt + 1 < nk) __syncthreads();   // staged tiles landed; bufs safe
        }

        float inv[4];
#pragma unroll
        for (int r = 0; r < 4; r++) inv[r] = 1.0f / lacc[r];
#pragma unroll
        for (int n = 0; n < 4; n++)
#pragma unroll
            for (int r = 0; r < 4; r++) {
                const int qq = q0 + quad * 4 + r;
                Out[(size_t)(b * SEQ + qq) * HIDDEN + h * HD + n * 16 + lm] =
                    f2bf(oacc[n][r] * inv[r]);
            }
    }
}

// ---------------- launcher ------------------------------------------------
extern "C" void kernel_launch(void* const* d_in, const int* in_sizes, int n_in,
                              void* d_out, int out_size, void* d_ws, size_t ws_size,
                              hipStream_t stream) {
    const float* x  = (const float*)d_in[0];
    const float* Wq = (const float*)d_in[1];
    const float* bq = (const float*)d_in[2];
    const float* Wk = (const float*)d_in[3];
    const float* bk = (const float*)d_in[4];
    const float* Wv = (const float*)d_in[5];
    const float* bv = (const float*)d_in[6];
    const float* Wo = (const float*)d_in[7];
    const float* bo = (const float*)d_in[8];
    float* out = (float*)d_out;

    char* ws = (char*)d_ws;
    const size_t SZ_X = (size_t)4096 * 1024 * 2;   // 8 MB bf16
    const size_t SZ_W = (size_t)1024 * 1024 * 2;   // 2 MB bf16
    u16* xb    = (u16*)(ws);
    u16* wqb   = (u16*)(ws + SZ_X);
    u16* wkb   = (u16*)(ws + SZ_X + SZ_W);
    u16* wvb   = (u16*)(ws + SZ_X + 2 * SZ_W);
    u16* wob   = (u16*)(ws + SZ_X + 3 * SZ_W);
    u16* Qb    = (u16*)(ws + SZ_X + 4 * SZ_W);
    u16* Kb    = (u16*)(ws + 2 * SZ_X + 4 * SZ_W);
    u16* Vtb   = (u16*)(ws + 3 * SZ_X + 4 * SZ_W);
    u16* attnb = (u16*)(ws + 4 * SZ_X + 4 * SZ_W);

    cvt_all<<<4096, 256, 0, stream>>>(x, Wq, Wk, Wv, Wo, xb, wqb, wkb, wvb, wob);
    gemm_qkv<<<dim3(24, 32), 256, 0, stream>>>(xb, wqb, wkb, wvb, bq, bk, bv, Qb, Kb, Vtb);
    attn_kernel<<<512, 256, 0, stream>>>(Qb, Kb, Vtb, attnb);
    gemm_out<<<dim3(8, 64), 256, 0, stream>>>(attnb, wob, bo, out);
}

// Round 5
// 186.707 us; speedup vs baseline: 1.2544x; 1.0031x over previous
//
#include <hip/hip_runtime.h>
#include <stdint.h>

// MultiHeadAttention: B=2, S=2048, HIDDEN=1024, NH=16, HD=64, causal.
// R18: attn only -- disentangle R17. KEEP: slot-XOR conflict-free P layout
//      (b64 write+read), v_cvt_pk_bf16_f32 packing, software pipeline
//      (K staged 2-ahead, V 1-ahead, QK(kt+1) inside P-write->read window).
//      DROP: grid-512 q-tile pairing (R17 refuted it: occupancy 26->17%,
//      2 blocks/CU static -- TLP loss beat the pipeline gain; every attn
//      regression this session has been an occupancy regression).
//      Grid back to 1024, balanced map (66 steps/CU), LDS 40960 = 160K/4.
// MFMA 16x16x32 bf16 layouts (HW-verified):
//   A/B frag: lane holds row[m=lane&15][k=(lane>>4)*8 + j]
//   C/D:      row=(lane>>4)*4+reg, col=lane&15
// Swapped QK^T: mfma(kf,qf) -> C[key][q]; lane holds keys n*16+quad*4+{0..3}
// for q=lm -> keys 4-aligned -> slot-granular (8B) P stores.

#define HIDDEN 1024
#define NH 16
#define HD 64
#define BATCH 2
#define SEQ 2048

typedef unsigned short u16;
typedef unsigned int u32;
typedef __attribute__((ext_vector_type(8))) short short8;   // 8 bf16
typedef __attribute__((ext_vector_type(4))) float f32x4;

typedef const __attribute__((address_space(1))) u32 gu32;
typedef __attribute__((address_space(3))) u32 lu32;

__device__ __forceinline__ u16 f2bf(float f) {
    u32 u = __float_as_uint(f);
    return (u16)((u + 0x7FFFu + ((u >> 16) & 1u)) >> 16);   // RNE
}

// ---------------- fused fp32 -> bf16 conversion (x + 4 weights) -----------
__global__ void cvt_all(const float* __restrict__ x, const float* __restrict__ Wq,
                        const float* __restrict__ Wk, const float* __restrict__ Wv,
                        const float* __restrict__ Wo, u16* __restrict__ xb,
                        u16* __restrict__ wqb, u16* __restrict__ wkb,
                        u16* __restrict__ wvb, u16* __restrict__ wob) {
    const int blk = blockIdx.x;
    const float* src; u16* dst; int base;
    if (blk < 2048)      { src = x;  dst = xb;  base = blk; }
    else if (blk < 2560) { src = Wq; dst = wqb; base = blk - 2048; }
    else if (blk < 3072) { src = Wk; dst = wkb; base = blk - 2560; }
    else if (blk < 3584) { src = Wv; dst = wvb; base = blk - 3072; }
    else                 { src = Wo; dst = wob; base = blk - 3584; }
    const int i = base * 256 + threadIdx.x;
    float4 a = ((const float4*)src)[2 * i];
    float4 b = ((const float4*)src)[2 * i + 1];
    union { u16 h[8]; uint4 v; } o;
    o.h[0] = f2bf(a.x); o.h[1] = f2bf(a.y); o.h[2] = f2bf(a.z); o.h[3] = f2bf(a.w);
    o.h[4] = f2bf(b.x); o.h[5] = f2bf(b.y); o.h[6] = f2bf(b.z); o.h[7] = f2bf(b.w);
    ((uint4*)dst)[i] = o.v;
}

// ---- async stage: 16 rows x 32 cols (64 B/row) per call, XOR-4 swizzle ----
__device__ __forceinline__ void stage16(const u16* __restrict__ G, int grow0,
                                        int k0, u16* lds, int rbase, int lane) {
    const int sr = lane >> 2;
    const int lc = (lane & 3) ^ (sr & 3);
    const u16* g = G + (size_t)(grow0 + rbase + sr) * 1024 + k0 + lc * 8;
    __builtin_amdgcn_global_load_lds((gu32*)g, (lu32*)(lds + rbase * 32), 16, 0, 0);
}

// ---------------- fused QKV projection ------------------------------------
// grid (24, 32). Q/K -> [B,H,S,D] direct; V -> [B,H,D,S] via LDS transpose.
__launch_bounds__(256, 3)
__global__ void gemm_qkv(const u16* __restrict__ A, const u16* __restrict__ Wqb,
                         const u16* __restrict__ Wkb, const u16* __restrict__ Wvb,
                         const float* __restrict__ bq, const float* __restrict__ bk,
                         const float* __restrict__ bv, u16* __restrict__ Qo,
                         u16* __restrict__ Ko, u16* __restrict__ Vo) {
    __shared__ u16 As[2][128 * 32];   // 2 x 8 KB
    __shared__ u16 Bs[2][128 * 32];   // 2 x 8 KB -> 32 KB total
    const int which = blockIdx.x >> 3;
    const int n0 = (blockIdx.x & 7) * 128;
    const int m0 = blockIdx.y * 128;
    const u16* Wt = (which == 0) ? Wqb : (which == 1) ? Wkb : Wvb;
    const float* bias = (which == 0) ? bq : (which == 1) ? bk : bv;
    u16* out = (which == 0) ? Qo : (which == 1) ? Ko : Vo;
    const float oscale = (which == 0) ? 0.18033688011112042f : 1.0f;  // log2e/8
    const int t = threadIdx.x;
    const int lane = t & 63, w = t >> 6, quad = lane >> 4, lm = lane & 15;
    const int wm = (w & 1) * 64, wn = (w >> 1) * 64;

    f32x4 acc[4][4] = {};

    auto stage = [&](int k0, int buf) {
        stage16(A, m0, k0, As[buf], w * 32, lane);
        stage16(A, m0, k0, As[buf], w * 32 + 16, lane);
        stage16(Wt, n0, k0, Bs[buf], w * 32, lane);
        stage16(Wt, n0, k0, Bs[buf], w * 32 + 16, lane);
    };

    stage(0, 0);
    __syncthreads();
    for (int k0 = 0; k0 < 1024; k0 += 32) {
        const int cur = (k0 >> 5) & 1;
        if (k0 + 32 < 1024) stage(k0 + 32, cur ^ 1);
        short8 af[4], bf[4];
        const int sw = (quad ^ (lm & 3)) * 8;   // swizzled slot offset (elems)
#pragma unroll
        for (int mi = 0; mi < 4; mi++)
            af[mi] = *(const short8*)(&As[cur][(wm + mi * 16 + lm) * 32] + sw);
#pragma unroll
        for (int ni = 0; ni < 4; ni++)
            bf[ni] = *(const short8*)(&Bs[cur][(wn + ni * 16 + lm) * 32] + sw);
#pragma unroll
        for (int mi = 0; mi < 4; mi++)
#pragma unroll
            for (int ni = 0; ni < 4; ni++)
                acc[mi][ni] = __builtin_amdgcn_mfma_f32_16x16x32_bf16(
                    af[mi], bf[ni], acc[mi][ni], 0, 0, 0);
        __syncthreads();   // drains vmcnt (next tile landed) + guards buf reuse
    }

    if (which == 2) {
        // V: per-wave LDS transpose -> coalesced [B,H,D,S] stores.
        u16* Tw = ((w < 2) ? (u16*)As : (u16*)Bs) + (w & 1) * 4096;
#pragma unroll
        for (int ni = 0; ni < 4; ni++) {
            const int n_loc = ni * 16 + lm;
            const float bv_ = bias[n0 + wn + n_loc];
#pragma unroll
            for (int mi = 0; mi < 4; mi++)
#pragma unroll
                for (int r = 0; r < 4; r++) {
                    const int m_loc = mi * 16 + quad * 4 + r;
                    Tw[n_loc * 64 + (((m_loc >> 3) ^ (n_loc & 7)) * 8) + (m_loc & 7)] =
                        f2bf(acc[mi][ni][r] + bv_);
                }
        }
        const int hh = (n0 + wn) >> 6;
        const int mg = m0 + wm;             // 64-aligned, never straddles batch
        const int bb = mg >> 11, s0 = mg & 2047;
        u16* outp = out + ((size_t)(bb * NH + hh) * HD) * SEQ;
        const int cm = lane & 7;            // logical m-chunk (8 elems)
#pragma unroll
        for (int i = 0; i < 8; i++) {
            const int n_loc = i * 8 + (lane >> 3);   // d
            short8 v = *(const short8*)(Tw + n_loc * 64 + ((cm ^ (n_loc & 7)) * 8));
            *(short8*)(outp + (size_t)n_loc * SEQ + s0 + cm * 8) = v;
        }
    } else {
#pragma unroll
        for (int ni = 0; ni < 4; ni++) {
            const int n = n0 + wn + ni * 16 + lm;
            const float bv_ = bias[n];
            const int h = n >> 6, d = n & 63;
#pragma unroll
            for (int mi = 0; mi < 4; mi++)
#pragma unroll
                for (int r = 0; r < 4; r++) {
                    const int m = m0 + wm + mi * 16 + quad * 4 + r;
                    const int b = m >> 11, s = m & 2047;
                    out[(((size_t)(b * NH + h) * SEQ + s) * HD) + d] =
                        f2bf((acc[mi][ni][r] + bv_) * oscale);
                }
        }
    }
}

// ---------------- output projection (R10, unchanged) ----------------------
__launch_bounds__(256, 2)
__global__ void gemm_out(const u16* __restrict__ A, const u16* __restrict__ Wt,
                         const float* __restrict__ bias, float* __restrict__ out) {
    __shared__ u16 As[2][64 * 32];    // 2 x 4 KB
    __shared__ u16 Bs[2][128 * 32];   // 2 x 8 KB -> 24 KB total
    const int n0 = blockIdx.x * 128;
    const int m0 = blockIdx.y * 64;
    const int t = threadIdx.x;
    const int lane = t & 63, w = t >> 6, quad = lane >> 4, lm = lane & 15;
    const int wm = (w & 1) * 32, wn = (w >> 1) * 64;

    f32x4 acc[2][4] = {};

    auto stage = [&](int k0, int buf) {
        stage16(A, m0, k0, As[buf], w * 16, lane);
        stage16(Wt, n0, k0, Bs[buf], w * 32, lane);
        stage16(Wt, n0, k0, Bs[buf], w * 32 + 16, lane);
    };

    stage(0, 0);
    __syncthreads();
    for (int k0 = 0; k0 < 1024; k0 += 32) {
        const int cur = (k0 >> 5) & 1;
        if (k0 + 32 < 1024) stage(k0 + 32, cur ^ 1);
        short8 af[2], bf[4];
        const int sw = (quad ^ (lm & 3)) * 8;
#pragma unroll
        for (int mi = 0; mi < 2; mi++)
            af[mi] = *(const short8*)(&As[cur][(wm + mi * 16 + lm) * 32] + sw);
#pragma unroll
        for (int ni = 0; ni < 4; ni++)
            bf[ni] = *(const short8*)(&Bs[cur][(wn + ni * 16 + lm) * 32] + sw);
#pragma unroll
        for (int mi = 0; mi < 2; mi++)
#pragma unroll
            for (int ni = 0; ni < 4; ni++)
                acc[mi][ni] = __builtin_amdgcn_mfma_f32_16x16x32_bf16(
                    af[mi], bf[ni], acc[mi][ni], 0, 0, 0);
        __syncthreads();
    }

#pragma unroll
    for (int ni = 0; ni < 4; ni++) {
        const int n = n0 + wn + ni * 16 + lm;
        const float bv_ = bias[n];
#pragma unroll
        for (int mi = 0; mi < 2; mi++)
#pragma unroll
            for (int r = 0; r < 4; r++) {
                const int m = m0 + wm + mi * 16 + quad * 4 + r;
                out[(size_t)m * 1024 + n] = acc[mi][ni][r] + bv_;
            }
    }
}

// ---------------- flash attention, causal (R18) ---------------------------
// Grid 1024 blocks, 256 thr = 4 waves; wave owns 16 q-rows; Q-tile 64,
// K-tile 64, double-buffered via global_load_lds; balanced 66-step/CU map.
// Software-pipelined: QK(kt+1) hides P-write->P-read latency of step kt.
// P row = 16 8B slots, physical slot = l^lm -> conflict-free b64 write+read.
__launch_bounds__(256, 4)
__global__ void attn_kernel(const u16* __restrict__ Q, const u16* __restrict__ K,
                            const u16* __restrict__ Vt, u16* __restrict__ Out) {
    __shared__ u16 Ks[2][64 * 64];    // 2 x 8 KB, swizzled
    __shared__ u16 Vs[2][64 * 64];    // 2 x 8 KB, swizzled
    __shared__ u16 Ps[4 * 16 * 64];   // 8 KB, slot-XOR layout -> 40960 B total
    const int t = threadIdx.x;
    const int lane = t & 63, w = t >> 6, quad = lane >> 4, lm = lane & 15;
    // balanced static schedule: CU c's 4 resident blocks sum to 66 steps
    const int i = blockIdx.x >> 5;
    const int qt = (i < 16) ? (31 - i) : (i - 16);
    const int bh = blockIdx.x & 31;
    const int b = bh >> 4, h = bh & 15;
    const size_t base = (size_t)(b * NH + h) * SEQ * HD;
    const u16* Qg = Q + base;
    const u16* Kg = K + base;
    const u16* Vg = Vt + base;
    const int q0 = qt * 64 + w * 16;
    const int nk = qt + 1;   // number of 64-key steps

    u16* Pw = Ps + w * 16 * 64;

    const int srow = (lane >> 3);          // 0..7 within 8-row group
    const int schunk = (lane & 7) ^ srow;  // source logical chunk (r&7 == srow)
    auto stage_k = [&](int kt, int buf) {
#pragma unroll
        for (int j = 0; j < 2; j++) {
            const int row = w * 16 + j * 8 + srow;
            const u16* gk = Kg + (size_t)(kt * 64 + row) * HD + schunk * 8;
            __builtin_amdgcn_global_load_lds((gu32*)gk, (lu32*)(&Ks[buf][(w * 16 + j * 8) * 64]), 16, 0, 0);
        }
    };
    auto stage_v = [&](int kt, int buf) {
#pragma unroll
        for (int j = 0; j < 2; j++) {
            const int row = w * 16 + j * 8 + srow;
            const u16* gv = Vg + (size_t)row * SEQ + kt * 64 + schunk * 8;
            __builtin_amdgcn_global_load_lds((gu32*)gv, (lu32*)(&Vs[buf][(w * 16 + j * 8) * 64]), 16, 0, 0);
        }
    };

    short8 qf[2];
#pragma unroll
    for (int kk = 0; kk < 2; kk++)
        qf[kk] = *(const short8*)(Qg + (size_t)(q0 + lm) * HD + kk * 32 + quad * 8);

    f32x4 oacc[4] = {};
    f32x4 lacc = {};
    f32x4 sacc[4];
    short8 ones;
#pragma unroll
    for (int j = 0; j < 8; j++) ones[j] = (short)0x3F80;   // bf16 1.0

    // swapped QK^T: sacc[n] = C[key][q], key = n*16+quad*4+reg, q = lm
    auto qk_tile = [&](const u16* Kc) {
        __builtin_amdgcn_s_setprio(1);
#pragma unroll
        for (int n = 0; n < 4; n++) {
            const int r = n * 16 + lm;
            const u16* rowp = Kc + r * 64;
            short8 kf0 = *(const short8*)(rowp + ((quad ^ (r & 7)) * 8));
            short8 kf1 = *(const short8*)(rowp + (((quad + 4) ^ (r & 7)) * 8));
            f32x4 a = {};
            a = __builtin_amdgcn_mfma_f32_16x16x32_bf16(kf0, qf[0], a, 0, 0, 0);
            a = __builtin_amdgcn_mfma_f32_16x16x32_bf16(kf1, qf[1], a, 0, 0, 0);
            sacc[n] = a;
        }
        __builtin_amdgcn_s_setprio(0);
    };

    // prologue: K0 -> Ks[0]; issue K1,V0; QK(0)
    stage_k(0, 0);
    __syncthreads();
    if (nk > 1) stage_k(1, 1);
    stage_v(0, 0);
    qk_tile(Ks[0]);
    __syncthreads();

    for (int kt = 0; kt < nk; kt++) {
        const int kb = kt & 1;
        if (kt + 2 < nk) stage_k(kt + 2, kb);
        if (kt + 1 < nk) stage_v(kt + 1, kb ^ 1);

        // mask (diagonal step only) + exp2 + pack + P-write
        if (kt == qt) {
#pragma unroll
            for (int n = 0; n < 4; n++)
#pragma unroll
                for (int r = 0; r < 4; r++)
                    if (n * 16 + quad * 4 + r > w * 16 + lm)
                        sacc[n][r] = -__builtin_inff();
        }
#pragma unroll
        for (int n = 0; n < 4; n++) {
            float e0 = exp2f(sacc[n][0]), e1 = exp2f(sacc[n][1]);
            float e2 = exp2f(sacc[n][2]), e3 = exp2f(sacc[n][3]);
            u32 lo, hi;
            asm("v_cvt_pk_bf16_f32 %0, %1, %2" : "=v"(lo) : "v"(e0), "v"(e1));
            asm("v_cvt_pk_bf16_f32 %0, %1, %2" : "=v"(hi) : "v"(e2), "v"(e3));
            const int pslot = (n * 4 + quad) ^ lm;     // 8B slot, conflict-free
            *(uint2*)(Pw + lm * 64 + pslot * 4) = (uint2){lo, hi};
        }
        // pf read: logical slots l0, l0+1 -> physical l^lm (b64 pair)
        short8 pf[2];
#pragma unroll
        for (int k4 = 0; k4 < 2; k4++) {
            const int l0 = k4 * 8 + quad * 2;
            uint2 a = *(const uint2*)(Pw + lm * 64 + ((l0 ^ lm) * 4));
            uint2 c = *(const uint2*)(Pw + lm * 64 + (((l0 + 1) ^ lm) * 4));
            union { short8 s; uint4 u; } m_;
            m_.u = (uint4){a.x, a.y, c.x, c.y};
            pf[k4] = m_.s;
        }
        // QK for NEXT tile (independent) -- hides the P LDS round-trip
        if (kt + 1 < nk) qk_tile(Ks[kb ^ 1]);
        // PV + row-sum
        __builtin_amdgcn_s_setprio(1);
#pragma unroll
        for (int n = 0; n < 4; n++) {
            const int r = n * 16 + lm;
            const u16* rowp = Vs[kb] + r * 64;
#pragma unroll
            for (int k4 = 0; k4 < 2; k4++) {
                short8 vf = *(const short8*)(rowp + (((k4 * 4 + quad) ^ (r & 7)) * 8));
                oacc[n] = __builtin_amdgcn_mfma_f32_16x16x32_bf16(pf[k4], vf, oacc[n], 0, 0, 0);
            }
        }
#pragma unroll
        for (int k4 = 0; k4 < 2; k4++)
            lacc = __builtin_amdgcn_mfma_f32_16x16x32_bf16(pf[k4], ones, lacc, 0, 0, 0);
        __builtin_amdgcn_s_setprio(0);

        if (kt + 1 < nk) __syncthreads();   // staged tiles landed; bufs safe
    }

    float inv[4];
#pragma unroll
    for (int r = 0; r < 4; r++) inv[r] = 1.0f / lacc[r];
#pragma unroll
    for (int n = 0; n < 4; n++)
#pragma unroll
        for (int r = 0; r < 4; r++) {
            const int qq = q0 + quad * 4 + r;
            Out[(size_t)(b * SEQ + qq) * HIDDEN + h * HD + n * 16 + lm] =
                f2bf(oacc[n][r] * inv[r]);
        }
}

// ---------------- launcher ------------------------------------------------
extern "C" void kernel_launch(void* const* d_in, const int* in_sizes, int n_in,
                              void* d_out, int out_size, void* d_ws, size_t ws_size,
                              hipStream_t stream) {
    const float* x  = (const float*)d_in[0];
    const float* Wq = (const float*)d_in[1];
    const float* bq = (const float*)d_in[2];
    const float* Wk = (const float*)d_in[3];
    const float* bk = (const float*)d_in[4];
    const float* Wv = (const float*)d_in[5];
    const float* bv = (const float*)d_in[6];
    const float* Wo = (const float*)d_in[7];
    const float* bo = (const float*)d_in[8];
    float* out = (float*)d_out;

    char* ws = (char*)d_ws;
    const size_t SZ_X = (size_t)4096 * 1024 * 2;   // 8 MB bf16
    const size_t SZ_W = (size_t)1024 * 1024 * 2;   // 2 MB bf16
    u16* xb    = (u16*)(ws);
    u16* wqb   = (u16*)(ws + SZ_X);
    u16* wkb   = (u16*)(ws + SZ_X + SZ_W);
    u16* wvb   = (u16*)(ws + SZ_X + 2 * SZ_W);
    u16* wob   = (u16*)(ws + SZ_X + 3 * SZ_W);
    u16* Qb    = (u16*)(ws + SZ_X + 4 * SZ_W);
    u16* Kb    = (u16*)(ws + 2 * SZ_X + 4 * SZ_W);
    u16* Vtb   = (u16*)(ws + 3 * SZ_X + 4 * SZ_W);
    u16* attnb = (u16*)(ws + 4 * SZ_X + 4 * SZ_W);

    cvt_all<<<4096, 256, 0, stream>>>(x, Wq, Wk, Wv, Wo, xb, wqb, wkb, wvb, wob);
    gemm_qkv<<<dim3(24, 32), 256, 0, stream>>>(xb, wqb, wkb, wvb, bq, bk, bv, Qb, Kb, Vtb);
    attn_kernel<<<BATCH * NH * (SEQ / 64), 256, 0, stream>>>(Qb, Kb, Vtb, attnb);
    gemm_out<<<dim3(8, 64), 256, 0, stream>>>(attnb, wob, bo, out);
}

// Round 6
// 186.031 us; speedup vs baseline: 1.2590x; 1.0036x over previous
//
#include <hip/hip_runtime.h>
#include <stdint.h>

// MultiHeadAttention: B=2, S=2048, HIDDEN=1024, NH=16, HD=64, causal.
// R19: GEMM bank-conflict fix only (attn untouched, R18 structure kept).
//      stage16's XOR-chunk swizzle used row bits [1:0]; fragment reads at
//      physical chunk quad^(lm&3) then put lanes {lm,lm+4,lm+8,lm+12} (same
//      chunk, same bank half, 4 distinct rows) on the SAME 4 banks -> uniform
//      4-way conflict on every ds_read_b128 (3.2M counted in gemm_qkv ~=
//      4 cyc/read ✓). Swizzle moved to row bits [3:2]: chunk c^((r>>2)&3)
//      -> same-chunk lane groups now hit distinct bank-groups, 2 lanes/bank
//      (free per m136). Write+read sides changed together (involution).
// MFMA 16x16x32 bf16 layouts (HW-verified):
//   A/B frag: lane holds row[m=lane&15][k=(lane>>4)*8 + j]
//   C/D:      row=(lane>>4)*4+reg, col=lane&15
// Swapped QK^T in attn: mfma(kf,qf) -> C[key][q]; keys 4-aligned per lane.

#define HIDDEN 1024
#define NH 16
#define HD 64
#define BATCH 2
#define SEQ 2048

typedef unsigned short u16;
typedef unsigned int u32;
typedef __attribute__((ext_vector_type(8))) short short8;   // 8 bf16
typedef __attribute__((ext_vector_type(4))) float f32x4;

typedef const __attribute__((address_space(1))) u32 gu32;
typedef __attribute__((address_space(3))) u32 lu32;

__device__ __forceinline__ u16 f2bf(float f) {
    u32 u = __float_as_uint(f);
    return (u16)((u + 0x7FFFu + ((u >> 16) & 1u)) >> 16);   // RNE
}

// ---------------- fused fp32 -> bf16 conversion (x + 4 weights) -----------
__global__ void cvt_all(const float* __restrict__ x, const float* __restrict__ Wq,
                        const float* __restrict__ Wk, const float* __restrict__ Wv,
                        const float* __restrict__ Wo, u16* __restrict__ xb,
                        u16* __restrict__ wqb, u16* __restrict__ wkb,
                        u16* __restrict__ wvb, u16* __restrict__ wob) {
    const int blk = blockIdx.x;
    const float* src; u16* dst; int base;
    if (blk < 2048)      { src = x;  dst = xb;  base = blk; }
    else if (blk < 2560) { src = Wq; dst = wqb; base = blk - 2048; }
    else if (blk < 3072) { src = Wk; dst = wkb; base = blk - 2560; }
    else if (blk < 3584) { src = Wv; dst = wvb; base = blk - 3072; }
    else                 { src = Wo; dst = wob; base = blk - 3584; }
    const int i = base * 256 + threadIdx.x;
    float4 a = ((const float4*)src)[2 * i];
    float4 b = ((const float4*)src)[2 * i + 1];
    union { u16 h[8]; uint4 v; } o;
    o.h[0] = f2bf(a.x); o.h[1] = f2bf(a.y); o.h[2] = f2bf(a.z); o.h[3] = f2bf(a.w);
    o.h[4] = f2bf(b.x); o.h[5] = f2bf(b.y); o.h[6] = f2bf(b.z); o.h[7] = f2bf(b.w);
    ((uint4*)dst)[i] = o.v;
}

// ---- async stage: 16 rows x 32 cols (64 B/row) per call ------------------
// XOR-chunk swizzle on row bits [3:2]: physical chunk c holds logical chunk
// c ^ ((row>>2)&3). (Row bits [1:0] gave 4-way read conflicts -- R19 note.)
__device__ __forceinline__ void stage16(const u16* __restrict__ G, int grow0,
                                        int k0, u16* lds, int rbase, int lane) {
    const int sr = lane >> 2;
    const int lc = (lane & 3) ^ ((sr >> 2) & 3);
    const u16* g = G + (size_t)(grow0 + rbase + sr) * 1024 + k0 + lc * 8;
    __builtin_amdgcn_global_load_lds((gu32*)g, (lu32*)(lds + rbase * 32), 16, 0, 0);
}

// ---------------- fused QKV projection ------------------------------------
// grid (24, 32). Q/K -> [B,H,S,D] direct; V -> [B,H,D,S] via LDS transpose.
__launch_bounds__(256, 3)
__global__ void gemm_qkv(const u16* __restrict__ A, const u16* __restrict__ Wqb,
                         const u16* __restrict__ Wkb, const u16* __restrict__ Wvb,
                         const float* __restrict__ bq, const float* __restrict__ bk,
                         const float* __restrict__ bv, u16* __restrict__ Qo,
                         u16* __restrict__ Ko, u16* __restrict__ Vo) {
    __shared__ u16 As[2][128 * 32];   // 2 x 8 KB
    __shared__ u16 Bs[2][128 * 32];   // 2 x 8 KB -> 32 KB total
    const int which = blockIdx.x >> 3;
    const int n0 = (blockIdx.x & 7) * 128;
    const int m0 = blockIdx.y * 128;
    const u16* Wt = (which == 0) ? Wqb : (which == 1) ? Wkb : Wvb;
    const float* bias = (which == 0) ? bq : (which == 1) ? bk : bv;
    u16* out = (which == 0) ? Qo : (which == 1) ? Ko : Vo;
    const float oscale = (which == 0) ? 0.18033688011112042f : 1.0f;  // log2e/8
    const int t = threadIdx.x;
    const int lane = t & 63, w = t >> 6, quad = lane >> 4, lm = lane & 15;
    const int wm = (w & 1) * 64, wn = (w >> 1) * 64;

    f32x4 acc[4][4] = {};

    auto stage = [&](int k0, int buf) {
        stage16(A, m0, k0, As[buf], w * 32, lane);
        stage16(A, m0, k0, As[buf], w * 32 + 16, lane);
        stage16(Wt, n0, k0, Bs[buf], w * 32, lane);
        stage16(Wt, n0, k0, Bs[buf], w * 32 + 16, lane);
    };

    stage(0, 0);
    __syncthreads();
    for (int k0 = 0; k0 < 1024; k0 += 32) {
        const int cur = (k0 >> 5) & 1;
        if (k0 + 32 < 1024) stage(k0 + 32, cur ^ 1);
        short8 af[4], bf[4];
        const int sw = (quad ^ ((lm >> 2) & 3)) * 8;   // swizzled slot (elems)
#pragma unroll
        for (int mi = 0; mi < 4; mi++)
            af[mi] = *(const short8*)(&As[cur][(wm + mi * 16 + lm) * 32] + sw);
#pragma unroll
        for (int ni = 0; ni < 4; ni++)
            bf[ni] = *(const short8*)(&Bs[cur][(wn + ni * 16 + lm) * 32] + sw);
#pragma unroll
        for (int mi = 0; mi < 4; mi++)
#pragma unroll
            for (int ni = 0; ni < 4; ni++)
                acc[mi][ni] = __builtin_amdgcn_mfma_f32_16x16x32_bf16(
                    af[mi], bf[ni], acc[mi][ni], 0, 0, 0);
        __syncthreads();   // drains vmcnt (next tile landed) + guards buf reuse
    }

    if (which == 2) {
        // V: per-wave LDS transpose -> coalesced [B,H,D,S] stores.
        u16* Tw = ((w < 2) ? (u16*)As : (u16*)Bs) + (w & 1) * 4096;
#pragma unroll
        for (int ni = 0; ni < 4; ni++) {
            const int n_loc = ni * 16 + lm;
            const float bv_ = bias[n0 + wn + n_loc];
#pragma unroll
            for (int mi = 0; mi < 4; mi++)
#pragma unroll
                for (int r = 0; r < 4; r++) {
                    const int m_loc = mi * 16 + quad * 4 + r;
                    Tw[n_loc * 64 + (((m_loc >> 3) ^ (n_loc & 7)) * 8) + (m_loc & 7)] =
                        f2bf(acc[mi][ni][r] + bv_);
                }
        }
        const int hh = (n0 + wn) >> 6;
        const int mg = m0 + wm;             // 64-aligned, never straddles batch
        const int bb = mg >> 11, s0 = mg & 2047;
        u16* outp = out + ((size_t)(bb * NH + hh) * HD) * SEQ;
        const int cm = lane & 7;            // logical m-chunk (8 elems)
#pragma unroll
        for (int i = 0; i < 8; i++) {
            const int n_loc = i * 8 + (lane >> 3);   // d
            short8 v = *(const short8*)(Tw + n_loc * 64 + ((cm ^ (n_loc & 7)) * 8));
            *(short8*)(outp + (size_t)n_loc * SEQ + s0 + cm * 8) = v;
        }
    } else {
#pragma unroll
        for (int ni = 0; ni < 4; ni++) {
            const int n = n0 + wn + ni * 16 + lm;
            const float bv_ = bias[n];
            const int h = n >> 6, d = n & 63;
#pragma unroll
            for (int mi = 0; mi < 4; mi++)
#pragma unroll
                for (int r = 0; r < 4; r++) {
                    const int m = m0 + wm + mi * 16 + quad * 4 + r;
                    const int b = m >> 11, s = m & 2047;
                    out[(((size_t)(b * NH + h) * SEQ + s) * HD) + d] =
                        f2bf((acc[mi][ni][r] + bv_) * oscale);
                }
        }
    }
}

// ---------------- output projection ---------------------------------------
__launch_bounds__(256, 2)
__global__ void gemm_out(const u16* __restrict__ A, const u16* __restrict__ Wt,
                         const float* __restrict__ bias, float* __restrict__ out) {
    __shared__ u16 As[2][64 * 32];    // 2 x 4 KB
    __shared__ u16 Bs[2][128 * 32];   // 2 x 8 KB -> 24 KB total
    const int n0 = blockIdx.x * 128;
    const int m0 = blockIdx.y * 64;
    const int t = threadIdx.x;
    const int lane = t & 63, w = t >> 6, quad = lane >> 4, lm = lane & 15;
    const int wm = (w & 1) * 32, wn = (w >> 1) * 64;

    f32x4 acc[2][4] = {};

    auto stage = [&](int k0, int buf) {
        stage16(A, m0, k0, As[buf], w * 16, lane);
        stage16(Wt, n0, k0, Bs[buf], w * 32, lane);
        stage16(Wt, n0, k0, Bs[buf], w * 32 + 16, lane);
    };

    stage(0, 0);
    __syncthreads();
    for (int k0 = 0; k0 < 1024; k0 += 32) {
        const int cur = (k0 >> 5) & 1;
        if (k0 + 32 < 1024) stage(k0 + 32, cur ^ 1);
        short8 af[2], bf[4];
        const int sw = (quad ^ ((lm >> 2) & 3)) * 8;
#pragma unroll
        for (int mi = 0; mi < 2; mi++)
            af[mi] = *(const short8*)(&As[cur][(wm + mi * 16 + lm) * 32] + sw);
#pragma unroll
        for (int ni = 0; ni < 4; ni++)
            bf[ni] = *(const short8*)(&Bs[cur][(wn + ni * 16 + lm) * 32] + sw);
#pragma unroll
        for (int mi = 0; mi < 2; mi++)
#pragma unroll
            for (int ni = 0; ni < 4; ni++)
                acc[mi][ni] = __builtin_amdgcn_mfma_f32_16x16x32_bf16(
                    af[mi], bf[ni], acc[mi][ni], 0, 0, 0);
        __syncthreads();
    }

#pragma unroll
    for (int ni = 0; ni < 4; ni++) {
        const int n = n0 + wn + ni * 16 + lm;
        const float bv_ = bias[n];
#pragma unroll
        for (int mi = 0; mi < 2; mi++)
#pragma unroll
            for (int r = 0; r < 4; r++) {
                const int m = m0 + wm + mi * 16 + quad * 4 + r;
                out[(size_t)m * 1024 + n] = acc[mi][ni][r] + bv_;
            }
    }
}

// ---------------- flash attention, causal (R18, unchanged) ----------------
// Grid 1024 blocks, 256 thr = 4 waves; wave owns 16 q-rows; Q-tile 64,
// K-tile 64, double-buffered via global_load_lds; balanced 66-step/CU map.
// Software-pipelined: QK(kt+1) hides P-write->P-read latency of step kt.
// P row = 16 8B slots, physical slot = l^lm -> conflict-free b64 write+read.
__launch_bounds__(256, 4)
__global__ void attn_kernel(const u16* __restrict__ Q, const u16* __restrict__ K,
                            const u16* __restrict__ Vt, u16* __restrict__ Out) {
    __shared__ u16 Ks[2][64 * 64];    // 2 x 8 KB, swizzled
    __shared__ u16 Vs[2][64 * 64];    // 2 x 8 KB, swizzled
    __shared__ u16 Ps[4 * 16 * 64];   // 8 KB, slot-XOR layout -> 40960 B total
    const int t = threadIdx.x;
    const int lane = t & 63, w = t >> 6, quad = lane >> 4, lm = lane & 15;
    // balanced static schedule: CU c's 4 resident blocks sum to 66 steps
    const int i = blockIdx.x >> 5;
    const int qt = (i < 16) ? (31 - i) : (i - 16);
    const int bh = blockIdx.x & 31;
    const int b = bh >> 4, h = bh & 15;
    const size_t base = (size_t)(b * NH + h) * SEQ * HD;
    const u16* Qg = Q + base;
    const u16* Kg = K + base;
    const u16* Vg = Vt + base;
    const int q0 = qt * 64 + w * 16;
    const int nk = qt + 1;   // number of 64-key steps

    u16* Pw = Ps + w * 16 * 64;

    const int srow = (lane >> 3);          // 0..7 within 8-row group
    const int schunk = (lane & 7) ^ srow;  // source logical chunk (r&7 == srow)
    auto stage_k = [&](int kt, int buf) {
#pragma unroll
        for (int j = 0; j < 2; j++) {
            const int row = w * 16 + j * 8 + srow;
            const u16* gk = Kg + (size_t)(kt * 64 + row) * HD + schunk * 8;
            __builtin_amdgcn_global_load_lds((gu32*)gk, (lu32*)(&Ks[buf][(w * 16 + j * 8) * 64]), 16, 0, 0);
        }
    };
    auto stage_v = [&](int kt, int buf) {
#pragma unroll
        for (int j = 0; j < 2; j++) {
            const int row = w * 16 + j * 8 + srow;
            const u16* gv = Vg + (size_t)row * SEQ + kt * 64 + schunk * 8;
            __builtin_amdgcn_global_load_lds((gu32*)gv, (lu32*)(&Vs[buf][(w * 16 + j * 8) * 64]), 16, 0, 0);
        }
    };

    short8 qf[2];
#pragma unroll
    for (int kk = 0; kk < 2; kk++)
        qf[kk] = *(const short8*)(Qg + (size_t)(q0 + lm) * HD + kk * 32 + quad * 8);

    f32x4 oacc[4] = {};
    f32x4 lacc = {};
    f32x4 sacc[4];
    short8 ones;
#pragma unroll
    for (int j = 0; j < 8; j++) ones[j] = (short)0x3F80;   // bf16 1.0

    // swapped QK^T: sacc[n] = C[key][q], key = n*16+quad*4+reg, q = lm
    auto qk_tile = [&](const u16* Kc) {
        __builtin_amdgcn_s_setprio(1);
#pragma unroll
        for (int n = 0; n < 4; n++) {
            const int r = n * 16 + lm;
            const u16* rowp = Kc + r * 64;
            short8 kf0 = *(const short8*)(rowp + ((quad ^ (r & 7)) * 8));
            short8 kf1 = *(const short8*)(rowp + (((quad + 4) ^ (r & 7)) * 8));
            f32x4 a = {};
            a = __builtin_amdgcn_mfma_f32_16x16x32_bf16(kf0, qf[0], a, 0, 0, 0);
            a = __builtin_amdgcn_mfma_f32_16x16x32_bf16(kf1, qf[1], a, 0, 0, 0);
            sacc[n] = a;
        }
        __builtin_amdgcn_s_setprio(0);
    };

    // prologue: K0 -> Ks[0]; issue K1,V0; QK(0)
    stage_k(0, 0);
    __syncthreads();
    if (nk > 1) stage_k(1, 1);
    stage_v(0, 0);
    qk_tile(Ks[0]);
    __syncthreads();

    for (int kt = 0; kt < nk; kt++) {
        const int kb = kt & 1;
        if (kt + 2 < nk) stage_k(kt + 2, kb);
        if (kt + 1 < nk) stage_v(kt + 1, kb ^ 1);

        // mask (diagonal step only) + exp2 + pack + P-write
        if (kt == qt) {
#pragma unroll
            for (int n = 0; n < 4; n++)
#pragma unroll
                for (int r = 0; r < 4; r++)
                    if (n * 16 + quad * 4 + r > w * 16 + lm)
                        sacc[n][r] = -__builtin_inff();
        }
#pragma unroll
        for (int n = 0; n < 4; n++) {
            float e0 = exp2f(sacc[n][0]), e1 = exp2f(sacc[n][1]);
            float e2 = exp2f(sacc[n][2]), e3 = exp2f(sacc[n][3]);
            u32 lo, hi;
            asm("v_cvt_pk_bf16_f32 %0, %1, %2" : "=v"(lo) : "v"(e0), "v"(e1));
            asm("v_cvt_pk_bf16_f32 %0, %1, %2" : "=v"(hi) : "v"(e2), "v"(e3));
            const int pslot = (n * 4 + quad) ^ lm;     // 8B slot, conflict-free
            *(uint2*)(Pw + lm * 64 + pslot * 4) = (uint2){lo, hi};
        }
        // pf read: logical slots l0, l0+1 -> physical l^lm (b64 pair)
        short8 pf[2];
#pragma unroll
        for (int k4 = 0; k4 < 2; k4++) {
            const int l0 = k4 * 8 + quad * 2;
            uint2 a = *(const uint2*)(Pw + lm * 64 + ((l0 ^ lm) * 4));
            uint2 c = *(const uint2*)(Pw + lm * 64 + (((l0 + 1) ^ lm) * 4));
            union { short8 s; uint4 u; } m_;
            m_.u = (uint4){a.x, a.y, c.x, c.y};
            pf[k4] = m_.s;
        }
        // QK for NEXT tile (independent) -- hides the P LDS round-trip
        if (kt + 1 < nk) qk_tile(Ks[kb ^ 1]);
        // PV + row-sum
        __builtin_amdgcn_s_setprio(1);
#pragma unroll
        for (int n = 0; n < 4; n++) {
            const int r = n * 16 + lm;
            const u16* rowp = Vs[kb] + r * 64;
#pragma unroll
            for (int k4 = 0; k4 < 2; k4++) {
                short8 vf = *(const short8*)(rowp + (((k4 * 4 + quad) ^ (r & 7)) * 8));
                oacc[n] = __builtin_amdgcn_mfma_f32_16x16x32_bf16(pf[k4], vf, oacc[n], 0, 0, 0);
            }
        }
#pragma unroll
        for (int k4 = 0; k4 < 2; k4++)
            lacc = __builtin_amdgcn_mfma_f32_16x16x32_bf16(pf[k4], ones, lacc, 0, 0, 0);
        __builtin_amdgcn_s_setprio(0);

        if (kt + 1 < nk) __syncthreads();   // staged tiles landed; bufs safe
    }

    float inv[4];
#pragma unroll
    for (int r = 0; r < 4; r++) inv[r] = 1.0f / lacc[r];
#pragma unroll
    for (int n = 0; n < 4; n++)
#pragma unroll
        for (int r = 0; r < 4; r++) {
            const int qq = q0 + quad * 4 + r;
            Out[(size_t)(b * SEQ + qq) * HIDDEN + h * HD + n * 16 + lm] =
                f2bf(oacc[n][r] * inv[r]);
        }
}

// ---------------- launcher ------------------------------------------------
extern "C" void kernel_launch(void* const* d_in, const int* in_sizes, int n_in,
                              void* d_out, int out_size, void* d_ws, size_t ws_size,
                              hipStream_t stream) {
    const float* x  = (const float*)d_in[0];
    const float* Wq = (const float*)d_in[1];
    const float* bq = (const float*)d_in[2];
    const float* Wk = (const float*)d_in[3];
    const float* bk = (const float*)d_in[4];
    const float* Wv = (const float*)d_in[5];
    const float* bv = (const float*)d_in[6];
    const float* Wo = (const float*)d_in[7];
    const float* bo = (const float*)d_in[8];
    float* out = (float*)d_out;

    char* ws = (char*)d_ws;
    const size_t SZ_X = (size_t)4096 * 1024 * 2;   // 8 MB bf16
    const size_t SZ_W = (size_t)1024 * 1024 * 2;   // 2 MB bf16
    u16* xb    = (u16*)(ws);
    u16* wqb   = (u16*)(ws + SZ_X);
    u16* wkb   = (u16*)(ws + SZ_X + SZ_W);
    u16* wvb   = (u16*)(ws + SZ_X + 2 * SZ_W);
    u16* wob   = (u16*)(ws + SZ_X + 3 * SZ_W);
    u16* Qb    = (u16*)(ws + SZ_X + 4 * SZ_W);
    u16* Kb    = (u16*)(ws + 2 * SZ_X + 4 * SZ_W);
    u16* Vtb   = (u16*)(ws + 3 * SZ_X + 4 * SZ_W);
    u16* attnb = (u16*)(ws + 4 * SZ_X + 4 * SZ_W);

    cvt_all<<<4096, 256, 0, stream>>>(x, Wq, Wk, Wv, Wo, xb, wqb, wkb, wvb, wob);
    gemm_qkv<<<dim3(24, 32), 256, 0, stream>>>(xb, wqb, wkb, wvb, bq, bk, bv, Qb, Kb, Vtb);
    attn_kernel<<<BATCH * NH * (SEQ / 64), 256, 0, stream>>>(Qb, Kb, Vtb, attnb);
    gemm_out<<<dim3(8, 64), 256, 0, stream>>>(attnb, wob, bo, out);
}

// Round 7
// 185.255 us; speedup vs baseline: 1.2643x; 1.0042x over previous
//
#include <hip/hip_runtime.h>
#include <stdint.h>

// MultiHeadAttention: B=2, S=2048, HIDDEN=1024, NH=16, HD=64, causal.
// R20: gemm_out rewritten 64x128/256thr -> 128x128/512thr (8 waves, 2Mx4N,
//      wave out 64x32). Accounting across rounds shows gemm_out ~40us just
//      under every top-5 cutoff at ~215 TF (half of qkv's 585): its 64x128
//      tile gave 8 MFMA/wave/barrier vs qkv's 16 -> 2x barrier drain per
//      FLOP. New config matches qkv's work-per-barrier ratio exactly.
//      R19 lesson kept in comments: fragment-read bank conflicts did NOT
//      move with swizzle change (3,211,264 both runs) -> whole-wave b128
//      scheduling; the 3.2M is the V-epilogue Tw write phase (fixed).
// MFMA 16x16x32 bf16 layouts (HW-verified):
//   A/B frag: lane holds row[m=lane&15][k=(lane>>4)*8 + j]
//   C/D:      row=(lane>>4)*4+reg, col=lane&15
// Swapped QK^T in attn: mfma(kf,qf) -> C[key][q]; keys 4-aligned per lane.

#define HIDDEN 1024
#define NH 16
#define HD 64
#define BATCH 2
#define SEQ 2048

typedef unsigned short u16;
typedef unsigned int u32;
typedef __attribute__((ext_vector_type(8))) short short8;   // 8 bf16
typedef __attribute__((ext_vector_type(4))) float f32x4;

typedef const __attribute__((address_space(1))) u32 gu32;
typedef __attribute__((address_space(3))) u32 lu32;

__device__ __forceinline__ u16 f2bf(float f) {
    u32 u = __float_as_uint(f);
    return (u16)((u + 0x7FFFu + ((u >> 16) & 1u)) >> 16);   // RNE
}

// ---------------- fused fp32 -> bf16 conversion (x + 4 weights) -----------
__global__ void cvt_all(const float* __restrict__ x, const float* __restrict__ Wq,
                        const float* __restrict__ Wk, const float* __restrict__ Wv,
                        const float* __restrict__ Wo, u16* __restrict__ xb,
                        u16* __restrict__ wqb, u16* __restrict__ wkb,
                        u16* __restrict__ wvb, u16* __restrict__ wob) {
    const int blk = blockIdx.x;
    const float* src; u16* dst; int base;
    if (blk < 2048)      { src = x;  dst = xb;  base = blk; }
    else if (blk < 2560) { src = Wq; dst = wqb; base = blk - 2048; }
    else if (blk < 3072) { src = Wk; dst = wkb; base = blk - 2560; }
    else if (blk < 3584) { src = Wv; dst = wvb; base = blk - 3072; }
    else                 { src = Wo; dst = wob; base = blk - 3584; }
    const int i = base * 256 + threadIdx.x;
    float4 a = ((const float4*)src)[2 * i];
    float4 b = ((const float4*)src)[2 * i + 1];
    union { u16 h[8]; uint4 v; } o;
    o.h[0] = f2bf(a.x); o.h[1] = f2bf(a.y); o.h[2] = f2bf(a.z); o.h[3] = f2bf(a.w);
    o.h[4] = f2bf(b.x); o.h[5] = f2bf(b.y); o.h[6] = f2bf(b.z); o.h[7] = f2bf(b.w);
    ((uint4*)dst)[i] = o.v;
}

// ---- async stage: 16 rows x 32 cols (64 B/row) per call ------------------
// XOR-chunk swizzle on row bits [3:2]: physical chunk c holds logical chunk
// c ^ ((row>>2)&3).
__device__ __forceinline__ void stage16(const u16* __restrict__ G, int grow0,
                                        int k0, u16* lds, int rbase, int lane) {
    const int sr = lane >> 2;
    const int lc = (lane & 3) ^ ((sr >> 2) & 3);
    const u16* g = G + (size_t)(grow0 + rbase + sr) * 1024 + k0 + lc * 8;
    __builtin_amdgcn_global_load_lds((gu32*)g, (lu32*)(lds + rbase * 32), 16, 0, 0);
}

// ---------------- fused QKV projection ------------------------------------
// grid (24, 32). Q/K -> [B,H,S,D] direct; V -> [B,H,D,S] via LDS transpose.
__launch_bounds__(256, 3)
__global__ void gemm_qkv(const u16* __restrict__ A, const u16* __restrict__ Wqb,
                         const u16* __restrict__ Wkb, const u16* __restrict__ Wvb,
                         const float* __restrict__ bq, const float* __restrict__ bk,
                         const float* __restrict__ bv, u16* __restrict__ Qo,
                         u16* __restrict__ Ko, u16* __restrict__ Vo) {
    __shared__ u16 As[2][128 * 32];   // 2 x 8 KB
    __shared__ u16 Bs[2][128 * 32];   // 2 x 8 KB -> 32 KB total
    const int which = blockIdx.x >> 3;
    const int n0 = (blockIdx.x & 7) * 128;
    const int m0 = blockIdx.y * 128;
    const u16* Wt = (which == 0) ? Wqb : (which == 1) ? Wkb : Wvb;
    const float* bias = (which == 0) ? bq : (which == 1) ? bk : bv;
    u16* out = (which == 0) ? Qo : (which == 1) ? Ko : Vo;
    const float oscale = (which == 0) ? 0.18033688011112042f : 1.0f;  // log2e/8
    const int t = threadIdx.x;
    const int lane = t & 63, w = t >> 6, quad = lane >> 4, lm = lane & 15;
    const int wm = (w & 1) * 64, wn = (w >> 1) * 64;

    f32x4 acc[4][4] = {};

    auto stage = [&](int k0, int buf) {
        stage16(A, m0, k0, As[buf], w * 32, lane);
        stage16(A, m0, k0, As[buf], w * 32 + 16, lane);
        stage16(Wt, n0, k0, Bs[buf], w * 32, lane);
        stage16(Wt, n0, k0, Bs[buf], w * 32 + 16, lane);
    };

    stage(0, 0);
    __syncthreads();
    for (int k0 = 0; k0 < 1024; k0 += 32) {
        const int cur = (k0 >> 5) & 1;
        if (k0 + 32 < 1024) stage(k0 + 32, cur ^ 1);
        short8 af[4], bf[4];
        const int sw = (quad ^ ((lm >> 2) & 3)) * 8;   // swizzled slot (elems)
#pragma unroll
        for (int mi = 0; mi < 4; mi++)
            af[mi] = *(const short8*)(&As[cur][(wm + mi * 16 + lm) * 32] + sw);
#pragma unroll
        for (int ni = 0; ni < 4; ni++)
            bf[ni] = *(const short8*)(&Bs[cur][(wn + ni * 16 + lm) * 32] + sw);
#pragma unroll
        for (int mi = 0; mi < 4; mi++)
#pragma unroll
            for (int ni = 0; ni < 4; ni++)
                acc[mi][ni] = __builtin_amdgcn_mfma_f32_16x16x32_bf16(
                    af[mi], bf[ni], acc[mi][ni], 0, 0, 0);
        __syncthreads();   // drains vmcnt (next tile landed) + guards buf reuse
    }

    if (which == 2) {
        // V: per-wave LDS transpose -> coalesced [B,H,D,S] stores.
        u16* Tw = ((w < 2) ? (u16*)As : (u16*)Bs) + (w & 1) * 4096;
#pragma unroll
        for (int ni = 0; ni < 4; ni++) {
            const int n_loc = ni * 16 + lm;
            const float bv_ = bias[n0 + wn + n_loc];
#pragma unroll
            for (int mi = 0; mi < 4; mi++)
#pragma unroll
                for (int r = 0; r < 4; r++) {
                    const int m_loc = mi * 16 + quad * 4 + r;
                    Tw[n_loc * 64 + (((m_loc >> 3) ^ (n_loc & 7)) * 8) + (m_loc & 7)] =
                        f2bf(acc[mi][ni][r] + bv_);
                }
        }
        const int hh = (n0 + wn) >> 6;
        const int mg = m0 + wm;             // 64-aligned, never straddles batch
        const int bb = mg >> 11, s0 = mg & 2047;
        u16* outp = out + ((size_t)(bb * NH + hh) * HD) * SEQ;
        const int cm = lane & 7;            // logical m-chunk (8 elems)
#pragma unroll
        for (int i = 0; i < 8; i++) {
            const int n_loc = i * 8 + (lane >> 3);   // d
            short8 v = *(const short8*)(Tw + n_loc * 64 + ((cm ^ (n_loc & 7)) * 8));
            *(short8*)(outp + (size_t)n_loc * SEQ + s0 + cm * 8) = v;
        }
    } else {
#pragma unroll
        for (int ni = 0; ni < 4; ni++) {
            const int n = n0 + wn + ni * 16 + lm;
            const float bv_ = bias[n];
            const int h = n >> 6, d = n & 63;
#pragma unroll
            for (int mi = 0; mi < 4; mi++)
#pragma unroll
                for (int r = 0; r < 4; r++) {
                    const int m = m0 + wm + mi * 16 + quad * 4 + r;
                    const int b = m >> 11, s = m & 2047;
                    out[(((size_t)(b * NH + h) * SEQ + s) * HD) + d] =
                        f2bf((acc[mi][ni][r] + bv_) * oscale);
                }
        }
    }
}

// ---------------- output projection (R20: 128x128 / 512 thr / 8 waves) ----
// grid (8, 32) = 256 blocks = 1/CU even. Wave grid 2Mx4N, wave out 64x32.
// 64 MFMA per block-K-step vs 16 KB staging = same ratio as gemm_qkv.
__launch_bounds__(512, 2)
__global__ void gemm_out(const u16* __restrict__ A, const u16* __restrict__ Wt,
                         const float* __restrict__ bias, float* __restrict__ out) {
    __shared__ u16 As[2][128 * 32];   // 2 x 8 KB
    __shared__ u16 Bs[2][128 * 32];   // 2 x 8 KB -> 32 KB total
    const int n0 = blockIdx.x * 128;
    const int m0 = blockIdx.y * 128;
    const int t = threadIdx.x;
    const int lane = t & 63, w = t >> 6, quad = lane >> 4, lm = lane & 15;
    const int wm = (w & 1) * 64, wn = (w >> 1) * 32;

    f32x4 acc[4][2] = {};

    auto stage = [&](int k0, int buf) {
        stage16(A, m0, k0, As[buf], w * 16, lane);
        stage16(Wt, n0, k0, Bs[buf], w * 16, lane);
    };

    stage(0, 0);
    __syncthreads();
    for (int k0 = 0; k0 < 1024; k0 += 32) {
        const int cur = (k0 >> 5) & 1;
        if (k0 + 32 < 1024) stage(k0 + 32, cur ^ 1);
        short8 af[4], bf[2];
        const int sw = (quad ^ ((lm >> 2) & 3)) * 8;
#pragma unroll
        for (int mi = 0; mi < 4; mi++)
            af[mi] = *(const short8*)(&As[cur][(wm + mi * 16 + lm) * 32] + sw);
#pragma unroll
        for (int ni = 0; ni < 2; ni++)
            bf[ni] = *(const short8*)(&Bs[cur][(wn + ni * 16 + lm) * 32] + sw);
#pragma unroll
        for (int mi = 0; mi < 4; mi++)
#pragma unroll
            for (int ni = 0; ni < 2; ni++)
                acc[mi][ni] = __builtin_amdgcn_mfma_f32_16x16x32_bf16(
                    af[mi], bf[ni], acc[mi][ni], 0, 0, 0);
        __syncthreads();
    }

#pragma unroll
    for (int ni = 0; ni < 2; ni++) {
        const int n = n0 + wn + ni * 16 + lm;
        const float bv_ = bias[n];
#pragma unroll
        for (int mi = 0; mi < 4; mi++)
#pragma unroll
            for (int r = 0; r < 4; r++) {
                const int m = m0 + wm + mi * 16 + quad * 4 + r;
                out[(size_t)m * 1024 + n] = acc[mi][ni][r] + bv_;
            }
    }
}

// ---------------- flash attention, causal (R18, unchanged) ----------------
// Grid 1024 blocks, 256 thr = 4 waves; wave owns 16 q-rows; Q-tile 64,
// K-tile 64, double-buffered via global_load_lds; balanced 66-step/CU map.
// Software-pipelined: QK(kt+1) hides P-write->P-read latency of step kt.
// P row = 16 8B slots, physical slot = l^lm -> conflict-free b64 write+read.
__launch_bounds__(256, 4)
__global__ void attn_kernel(const u16* __restrict__ Q, const u16* __restrict__ K,
                            const u16* __restrict__ Vt, u16* __restrict__ Out) {
    __shared__ u16 Ks[2][64 * 64];    // 2 x 8 KB, swizzled
    __shared__ u16 Vs[2][64 * 64];    // 2 x 8 KB, swizzled
    __shared__ u16 Ps[4 * 16 * 64];   // 8 KB, slot-XOR layout -> 40960 B total
    const int t = threadIdx.x;
    const int lane = t & 63, w = t >> 6, quad = lane >> 4, lm = lane & 15;
    // balanced static schedule: CU c's 4 resident blocks sum to 66 steps
    const int i = blockIdx.x >> 5;
    const int qt = (i < 16) ? (31 - i) : (i - 16);
    const int bh = blockIdx.x & 31;
    const int b = bh >> 4, h = bh & 15;
    const size_t base = (size_t)(b * NH + h) * SEQ * HD;
    const u16* Qg = Q + base;
    const u16* Kg = K + base;
    const u16* Vg = Vt + base;
    const int q0 = qt * 64 + w * 16;
    const int nk = qt + 1;   // number of 64-key steps

    u16* Pw = Ps + w * 16 * 64;

    const int srow = (lane >> 3);          // 0..7 within 8-row group
    const int schunk = (lane & 7) ^ srow;  // source logical chunk (r&7 == srow)
    auto stage_k = [&](int kt, int buf) {
#pragma unroll
        for (int j = 0; j < 2; j++) {
            const int row = w * 16 + j * 8 + srow;
            const u16* gk = Kg + (size_t)(kt * 64 + row) * HD + schunk * 8;
            __builtin_amdgcn_global_load_lds((gu32*)gk, (lu32*)(&Ks[buf][(w * 16 + j * 8) * 64]), 16, 0, 0);
        }
    };
    auto stage_v = [&](int kt, int buf) {
#pragma unroll
        for (int j = 0; j < 2; j++) {
            const int row = w * 16 + j * 8 + srow;
            const u16* gv = Vg + (size_t)row * SEQ + kt * 64 + schunk * 8;
            __builtin_amdgcn_global_load_lds((gu32*)gv, (lu32*)(&Vs[buf][(w * 16 + j * 8) * 64]), 16, 0, 0);
        }
    };

    short8 qf[2];
#pragma unroll
    for (int kk = 0; kk < 2; kk++)
        qf[kk] = *(const short8*)(Qg + (size_t)(q0 + lm) * HD + kk * 32 + quad * 8);

    f32x4 oacc[4] = {};
    f32x4 lacc = {};
    f32x4 sacc[4];
    short8 ones;
#pragma unroll
    for (int j = 0; j < 8; j++) ones[j] = (short)0x3F80;   // bf16 1.0

    // swapped QK^T: sacc[n] = C[key][q], key = n*16+quad*4+reg, q = lm
    auto qk_tile = [&](const u16* Kc) {
        __builtin_amdgcn_s_setprio(1);
#pragma unroll
        for (int n = 0; n < 4; n++) {
            const int r = n * 16 + lm;
            const u16* rowp = Kc + r * 64;
            short8 kf0 = *(const short8*)(rowp + ((quad ^ (r & 7)) * 8));
            short8 kf1 = *(const short8*)(rowp + (((quad + 4) ^ (r & 7)) * 8));
            f32x4 a = {};
            a = __builtin_amdgcn_mfma_f32_16x16x32_bf16(kf0, qf[0], a, 0, 0, 0);
            a = __builtin_amdgcn_mfma_f32_16x16x32_bf16(kf1, qf[1], a, 0, 0, 0);
            sacc[n] = a;
        }
        __builtin_amdgcn_s_setprio(0);
    };

    // prologue: K0 -> Ks[0]; issue K1,V0; QK(0)
    stage_k(0, 0);
    __syncthreads();
    if (nk > 1) stage_k(1, 1);
    stage_v(0, 0);
    qk_tile(Ks[0]);
    __syncthreads();

    for (int kt = 0; kt < nk; kt++) {
        const int kb = kt & 1;
        if (kt + 2 < nk) stage_k(kt + 2, kb);
        if (kt + 1 < nk) stage_v(kt + 1, kb ^ 1);

        // mask (diagonal step only) + exp2 + pack + P-write
        if (kt == qt) {
#pragma unroll
            for (int n = 0; n < 4; n++)
#pragma unroll
                for (int r = 0; r < 4; r++)
                    if (n * 16 + quad * 4 + r > w * 16 + lm)
                        sacc[n][r] = -__builtin_inff();
        }
#pragma unroll
        for (int n = 0; n < 4; n++) {
            float e0 = exp2f(sacc[n][0]), e1 = exp2f(sacc[n][1]);
            float e2 = exp2f(sacc[n][2]), e3 = exp2f(sacc[n][3]);
            u32 lo, hi;
            asm("v_cvt_pk_bf16_f32 %0, %1, %2" : "=v"(lo) : "v"(e0), "v"(e1));
            asm("v_cvt_pk_bf16_f32 %0, %1, %2" : "=v"(hi) : "v"(e2), "v"(e3));
            const int pslot = (n * 4 + quad) ^ lm;     // 8B slot, conflict-free
            *(uint2*)(Pw + lm * 64 + pslot * 4) = (uint2){lo, hi};
        }
        // pf read: logical slots l0, l0+1 -> physical l^lm (b64 pair)
        short8 pf[2];
#pragma unroll
        for (int k4 = 0; k4 < 2; k4++) {
            const int l0 = k4 * 8 + quad * 2;
            uint2 a = *(const uint2*)(Pw + lm * 64 + ((l0 ^ lm) * 4));
            uint2 c = *(const uint2*)(Pw + lm * 64 + (((l0 + 1) ^ lm) * 4));
            union { short8 s; uint4 u; } m_;
            m_.u = (uint4){a.x, a.y, c.x, c.y};
            pf[k4] = m_.s;
        }
        // QK for NEXT tile (independent) -- hides the P LDS round-trip
        if (kt + 1 < nk) qk_tile(Ks[kb ^ 1]);
        // PV + row-sum
        __builtin_amdgcn_s_setprio(1);
#pragma unroll
        for (int n = 0; n < 4; n++) {
            const int r = n * 16 + lm;
            const u16* rowp = Vs[kb] + r * 64;
#pragma unroll
            for (int k4 = 0; k4 < 2; k4++) {
                short8 vf = *(const short8*)(rowp + (((k4 * 4 + quad) ^ (r & 7)) * 8));
                oacc[n] = __builtin_amdgcn_mfma_f32_16x16x32_bf16(pf[k4], vf, oacc[n], 0, 0, 0);
            }
        }
#pragma unroll
        for (int k4 = 0; k4 < 2; k4++)
            lacc = __builtin_amdgcn_mfma_f32_16x16x32_bf16(pf[k4], ones, lacc, 0, 0, 0);
        __builtin_amdgcn_s_setprio(0);

        if (kt + 1 < nk) __syncthreads();   // staged tiles landed; bufs safe
    }

    float inv[4];
#pragma unroll
    for (int r = 0; r < 4; r++) inv[r] = 1.0f / lacc[r];
#pragma unroll
    for (int n = 0; n < 4; n++)
#pragma unroll
        for (int r = 0; r < 4; r++) {
            const int qq = q0 + quad * 4 + r;
            Out[(size_t)(b * SEQ + qq) * HIDDEN + h * HD + n * 16 + lm] =
                f2bf(oacc[n][r] * inv[r]);
        }
}

// ---------------- launcher ------------------------------------------------
extern "C" void kernel_launch(void* const* d_in, const int* in_sizes, int n_in,
                              void* d_out, int out_size, void* d_ws, size_t ws_size,
                              hipStream_t stream) {
    const float* x  = (const float*)d_in[0];
    const float* Wq = (const float*)d_in[1];
    const float* bq = (const float*)d_in[2];
    const float* Wk = (const float*)d_in[3];
    const float* bk = (const float*)d_in[4];
    const float* Wv = (const float*)d_in[5];
    const float* bv = (const float*)d_in[6];
    const float* Wo = (const float*)d_in[7];
    const float* bo = (const float*)d_in[8];
    float* out = (float*)d_out;

    char* ws = (char*)d_ws;
    const size_t SZ_X = (size_t)4096 * 1024 * 2;   // 8 MB bf16
    const size_t SZ_W = (size_t)1024 * 1024 * 2;   // 2 MB bf16
    u16* xb    = (u16*)(ws);
    u16* wqb   = (u16*)(ws + SZ_X);
    u16* wkb   = (u16*)(ws + SZ_X + SZ_W);
    u16* wvb   = (u16*)(ws + SZ_X + 2 * SZ_W);
    u16* wob   = (u16*)(ws + SZ_X + 3 * SZ_W);
    u16* Qb    = (u16*)(ws + SZ_X + 4 * SZ_W);
    u16* Kb    = (u16*)(ws + 2 * SZ_X + 4 * SZ_W);
    u16* Vtb   = (u16*)(ws + 3 * SZ_X + 4 * SZ_W);
    u16* attnb = (u16*)(ws + 4 * SZ_X + 4 * SZ_W);

    cvt_all<<<4096, 256, 0, stream>>>(x, Wq, Wk, Wv, Wo, xb, wqb, wkb, wvb, wob);
    gemm_qkv<<<dim3(24, 32), 256, 0, stream>>>(xb, wqb, wkb, wvb, bq, bk, bv, Qb, Kb, Vtb);
    attn_kernel<<<BATCH * NH * (SEQ / 64), 256, 0, stream>>>(Qb, Kb, Vtb, attnb);
    gemm_out<<<dim3(8, 32), 512, 0, stream>>>(attnb, wob, bo, out);
}